// Round 5
// baseline (1273.920 us; speedup 1.0000x reference)
//
#include <hip/hip_runtime.h>
#include <math.h>

// ConvKAN3D: conv3d(3x3x3,pad1) -> cubic KAN spline + SiLU -> BN(eval) -> maxpool 2x2x2, x3
// L1: fused single kernel (cin=1). L2/L3: two-phase (conv partials with cin-chunk
// split + atomicAdd into zeroed conv buffer; then spline/pool epilogue) so the
// channel-heavy layers get enough blocks to fill 256 CUs.
// LDS tile staged via global_load_lds (zero VGPR), double-buffered, borders pre-zeroed.
// Row swizzle: phys = logical + ((hy>>1)&1) dwords -> stride-2 lane reads cover all
// 32 banks (2-way, free) instead of 16 banks (4-way).

#define GLOBAL_AS __attribute__((address_space(1)))
#define LDS_AS    __attribute__((address_space(3)))

static __device__ __forceinline__ void async_ld4(const float* g, float* l) {
    __builtin_amdgcn_global_load_lds((const GLOBAL_AS void*)g, (LDS_AS void*)l,
                                     4, 0, 0);
}

// ---------------- fused kernel (used for L1, CIN=1) ----------------
template <int TPB_, int CIN, int G, int PDT, int PHT, int PWT>
__global__ __launch_bounds__(TPB_, 3) void spline_block_kernel(
    const float* __restrict__ x, const float* __restrict__ cw,
    const float* __restrict__ cb, const float* __restrict__ knots,
    const float* __restrict__ sw, const float* __restrict__ w1,
    const float* __restrict__ w2, const float* __restrict__ g,
    const float* __restrict__ beta, float* __restrict__ out,
    int N, int Cout, int D, int H, int W,
    int ntiles, int nthw, int ntw)
{
    constexpr int ID    = 2 * PDT + 2;
    constexpr int IH    = 2 * PHT + 2;
    constexpr int IW    = 2 * PWT + 2;
    constexpr int PITCH = 20;
    static_assert(IW + 1 <= PITCH, "tile width + swizzle fits pitch");
    constexpr int PHYS  = ID * IH * PITCH;
    constexpr int NST   = (PHYS + TPB_ - 1) / TPB_;
    constexpr int BUFS  = (CIN > 1) ? 2 : 1;
    static_assert(NST <= 32, "mask fits u32");
    static_assert(PDT * PHT * PWT == TPB_, "one thread per pooled voxel");

    __shared__ float tile[BUFS][PHYS];
    __shared__ float wlds[CIN * G * 28];

    const int PD = D >> 1, PH = H >> 1, PW = W >> 1;
    const int groups = Cout / G;
    const int tid = threadIdx.x;
    const int wbase = tid & ~63;

    const int bx      = blockIdx.x;
    const int tile_id = bx % ntiles;
    const int t1      = bx / ntiles;
    const int grp     = t1 % groups;
    const int n       = t1 / groups;
    const int c0      = grp * G;

    const int td  = tile_id / nthw;
    const int rem = tile_id % nthw;
    const int th_ = rem / ntw;
    const int tw_ = rem % ntw;

    for (int i = tid; i < BUFS * PHYS; i += TPB_)
        (&tile[0][0])[i] = 0.0f;
    for (int i = tid; i < CIN * G * 27; i += TPB_) {
        const int t  = i % 27;
        const int cg = i / 27;
        const int gg = cg % G;
        const int ci = cg / G;
        wlds[cg * 28 + t] = cw[((c0 + gg) * CIN + ci) * 27 + t];
    }

    const int pwl = tid % PWT;
    const int phl = (tid / PWT) % PHT;
    const int pdl = tid / (PWT * PHT);

    const int pd0 = td * PDT, ph0 = th_ * PHT, pw0 = tw_ * PWT;
    const int d0 = 2 * pd0 - 1, h0 = 2 * ph0 - 1, w0 = 2 * pw0 - 1;

    int offg[NST];
    unsigned vmask = 0;
#pragma unroll
    for (int k = 0; k < NST; k++) {
        const int p   = tid + TPB_ * k;
        const int wxs = p % PITCH;
        const int row = p / PITCH;
        const int hy  = row % IH;
        const int dz  = row / IH;
        const int wx  = wxs - ((hy >> 1) & 1);   // undo swizzle
        const int dd = d0 + dz, hh = h0 + hy, ww = w0 + wx;
        const bool ok = (p < PHYS) & (wx >= 0) & (wx < IW) &
                        ((unsigned)dd < (unsigned)D) &
                        ((unsigned)hh < (unsigned)H) &
                        ((unsigned)ww < (unsigned)W);
        offg[k] = ok ? (dd * H + hh) * W + ww : 0;
        vmask |= (unsigned)ok << k;
    }

    const size_t chstride = (size_t)D * H * W;
    const float* xn = x + (size_t)n * CIN * chstride;

    float acc[G][8];
#pragma unroll
    for (int gg = 0; gg < G; gg++) {
        const float bias = cb[c0 + gg];
#pragma unroll
        for (int i = 0; i < 8; i++) acc[gg][i] = bias;
    }

    __syncthreads();
    {
#pragma unroll
        for (int k = 0; k < NST; k++)
            if ((vmask >> k) & 1)
                async_ld4(xn + offg[k], &tile[0][TPB_ * k + wbase]);
    }
    __syncthreads();

    int cur = 0;
#pragma unroll 1
    for (int ci = 0; ci < CIN; ci++) {
        if (ci + 1 < CIN) {
            const float* xc = xn + (size_t)(ci + 1) * chstride;
#pragma unroll
            for (int k = 0; k < NST; k++)
                if ((vmask >> k) & 1)
                    async_ld4(xc + offg[k], &tile[cur ^ 1][TPB_ * k + wbase]);
        }

        const float* tb = &tile[cur][0];
        float r[64];
#pragma unroll
        for (int dz = 0; dz < 4; dz++)
#pragma unroll
        for (int dy = 0; dy < 4; dy++) {
            const int hy = 2 * phl + dy;
            const int base = ((2 * pdl + dz) * IH + hy) * PITCH + 2 * pwl +
                             ((hy >> 1) & 1);
            const float2 v0 = *(const float2*)(tb + base);
            const float2 v1 = *(const float2*)(tb + base + 2);
            r[(dz * 4 + dy) * 4 + 0] = v0.x;
            r[(dz * 4 + dy) * 4 + 1] = v0.y;
            r[(dz * 4 + dy) * 4 + 2] = v1.x;
            r[(dz * 4 + dy) * 4 + 3] = v1.y;
        }

#pragma unroll
        for (int gg = 0; gg < G; gg++) {
            const float4* w4p = (const float4*)&wlds[(ci * G + gg) * 28];
#pragma unroll
            for (int ch = 0; ch < 7; ch++) {
                const float4 wv = w4p[ch];
#pragma unroll
                for (int j = 0; j < 4; j++) {
                    const int tap = ch * 4 + j;
                    if (tap < 27) {
                        const float wvj = (j == 0) ? wv.x : (j == 1) ? wv.y
                                        : (j == 2) ? wv.z : wv.w;
                        const int kd = tap / 9, kh = (tap % 9) / 3, kw = tap % 3;
#pragma unroll
                        for (int od = 0; od < 2; od++)
#pragma unroll
                        for (int oh = 0; oh < 2; oh++)
#pragma unroll
                        for (int ow = 0; ow < 2; ow++)
                            acc[gg][(od * 2 + oh) * 2 + ow] =
                                fmaf(wvj,
                                     r[((od + kd) * 4 + (oh + kh)) * 4 + (ow + kw)],
                                     acc[gg][(od * 2 + oh) * 2 + ow]);
                    }
                }
            }
        }

        if (ci + 1 < CIN) {
            __syncthreads();
            cur ^= 1;
        }
    }

    float kn[10];
#pragma unroll
    for (int k = 0; k < 10; k++) kn[k] = knots[k];

    const int pdg = pd0 + pdl, phg = ph0 + phl, pwg = pw0 + pwl;
#pragma unroll
    for (int gg = 0; gg < G; gg++) {
        const int c = c0 + gg;
        float sc[10];
#pragma unroll
        for (int k = 0; k < 10; k++) sc[k] = sw[c * 10 + k];
        const float W1 = w1[c], W2 = w2[c];
        const float scale = g[c] * rsqrtf(1.0f + 1e-5f);
        const float bb = beta[c];

        float m = -INFINITY;
#pragma unroll
        for (int i = 0; i < 8; i++) {
            const float y = acc[gg][i];
            float sp = 0.0f;
#pragma unroll
            for (int k = 0; k < 10; k++) {
                const float tt = fmaxf(y - kn[k], 0.0f);
                sp = fmaf(tt * tt * tt, sc[k], sp);
            }
            const float silu = y / (1.0f + __expf(-y));
            const float o = fmaf(W1 * sp + W2 * silu, scale, bb);
            m = fmaxf(m, o);
        }
        out[((size_t)(n * Cout + c) * PD + pdg) * PH * PW + phg * PW + pwg] = m;
    }
}

// ---------------- phase A: conv partials over a cin-chunk, atomicAdd ----------------
template <int TPB_, int CHUNK, int G, int PDT, int PHT, int PWT>
__global__ __launch_bounds__(TPB_, 3) void conv_partial_kernel(
    const float* __restrict__ x,   // [N, CIN, D, D, D]
    const float* __restrict__ cw,  // [Cout, CIN, 27]
    float* __restrict__ convbuf,   // [N, Cout, D, D, D] (pre-zeroed)
    int N, int CIN, int Cout, int D,
    int ntiles, int nthw, int ntw, int nchunks)
{
    constexpr int ID    = 2 * PDT + 2;
    constexpr int IH    = 2 * PHT + 2;
    constexpr int IW    = 2 * PWT + 2;
    constexpr int PITCH = 20;
    static_assert(IW + 1 <= PITCH, "fits");
    constexpr int PHYS  = ID * IH * PITCH;
    constexpr int NST   = (PHYS + TPB_ - 1) / TPB_;
    static_assert(NST <= 32, "mask fits u32");
    static_assert(PDT * PHT * PWT == TPB_, "one thread per pooled voxel");

    __shared__ float tile[2][PHYS];
    __shared__ float wlds[CHUNK * G * 28];

    const int groups = Cout / G;
    const int tid = threadIdx.x;
    const int wbase = tid & ~63;

    const int bx      = blockIdx.x;
    const int tile_id = bx % ntiles;
    int t1            = bx / ntiles;
    const int chunk   = t1 % nchunks;
    t1               /= nchunks;
    const int grp     = t1 % groups;
    const int n       = t1 / groups;
    const int c0      = grp * G;
    const int cin0    = chunk * CHUNK;

    const int td  = tile_id / nthw;
    const int rem = tile_id % nthw;
    const int th_ = rem / ntw;
    const int tw_ = rem % ntw;

    for (int i = tid; i < 2 * PHYS; i += TPB_)
        (&tile[0][0])[i] = 0.0f;
    for (int i = tid; i < CHUNK * G * 27; i += TPB_) {
        const int t  = i % 27;
        const int cg = i / 27;
        const int gg = cg % G;
        const int ci = cg / G;
        wlds[cg * 28 + t] = cw[((c0 + gg) * CIN + cin0 + ci) * 27 + t];
    }

    const int pwl = tid % PWT;
    const int phl = (tid / PWT) % PHT;
    const int pdl = tid / (PWT * PHT);

    const int pd0 = td * PDT, ph0 = th_ * PHT, pw0 = tw_ * PWT;
    const int d0 = 2 * pd0 - 1, h0 = 2 * ph0 - 1, w0 = 2 * pw0 - 1;

    int offg[NST];
    unsigned vmask = 0;
#pragma unroll
    for (int k = 0; k < NST; k++) {
        const int p   = tid + TPB_ * k;
        const int wxs = p % PITCH;
        const int row = p / PITCH;
        const int hy  = row % IH;
        const int dz  = row / IH;
        const int wx  = wxs - ((hy >> 1) & 1);
        const int dd = d0 + dz, hh = h0 + hy, ww = w0 + wx;
        const bool ok = (p < PHYS) & (wx >= 0) & (wx < IW) &
                        ((unsigned)dd < (unsigned)D) &
                        ((unsigned)hh < (unsigned)D) &
                        ((unsigned)ww < (unsigned)D);
        offg[k] = ok ? (dd * D + hh) * D + ww : 0;
        vmask |= (unsigned)ok << k;
    }

    const size_t chstride = (size_t)D * D * D;
    const float* xn = x + ((size_t)n * CIN + cin0) * chstride;

    float acc[G][8];
#pragma unroll
    for (int gg = 0; gg < G; gg++)
#pragma unroll
        for (int i = 0; i < 8; i++) acc[gg][i] = 0.0f;

    __syncthreads();
    {
#pragma unroll
        for (int k = 0; k < NST; k++)
            if ((vmask >> k) & 1)
                async_ld4(xn + offg[k], &tile[0][TPB_ * k + wbase]);
    }
    __syncthreads();

    int cur = 0;
#pragma unroll 1
    for (int ci = 0; ci < CHUNK; ci++) {
        if (ci + 1 < CHUNK) {
            const float* xc = xn + (size_t)(ci + 1) * chstride;
#pragma unroll
            for (int k = 0; k < NST; k++)
                if ((vmask >> k) & 1)
                    async_ld4(xc + offg[k], &tile[cur ^ 1][TPB_ * k + wbase]);
        }

        const float* tb = &tile[cur][0];
        float r[64];
#pragma unroll
        for (int dz = 0; dz < 4; dz++)
#pragma unroll
        for (int dy = 0; dy < 4; dy++) {
            const int hy = 2 * phl + dy;
            const int base = ((2 * pdl + dz) * IH + hy) * PITCH + 2 * pwl +
                             ((hy >> 1) & 1);
            const float2 v0 = *(const float2*)(tb + base);
            const float2 v1 = *(const float2*)(tb + base + 2);
            r[(dz * 4 + dy) * 4 + 0] = v0.x;
            r[(dz * 4 + dy) * 4 + 1] = v0.y;
            r[(dz * 4 + dy) * 4 + 2] = v1.x;
            r[(dz * 4 + dy) * 4 + 3] = v1.y;
        }

#pragma unroll
        for (int gg = 0; gg < G; gg++) {
            const float4* w4p = (const float4*)&wlds[(ci * G + gg) * 28];
#pragma unroll
            for (int ch = 0; ch < 7; ch++) {
                const float4 wv = w4p[ch];
#pragma unroll
                for (int j = 0; j < 4; j++) {
                    const int tap = ch * 4 + j;
                    if (tap < 27) {
                        const float wvj = (j == 0) ? wv.x : (j == 1) ? wv.y
                                        : (j == 2) ? wv.z : wv.w;
                        const int kd = tap / 9, kh = (tap % 9) / 3, kw = tap % 3;
#pragma unroll
                        for (int od = 0; od < 2; od++)
#pragma unroll
                        for (int oh = 0; oh < 2; oh++)
#pragma unroll
                        for (int ow = 0; ow < 2; ow++)
                            acc[gg][(od * 2 + oh) * 2 + ow] =
                                fmaf(wvj,
                                     r[((od + kd) * 4 + (oh + kh)) * 4 + (ow + kw)],
                                     acc[gg][(od * 2 + oh) * 2 + ow]);
                    }
                }
            }
        }

        if (ci + 1 < CHUNK) {
            __syncthreads();
            cur ^= 1;
        }
    }

    // atomically accumulate partial conv outputs
    const int dg = 2 * (pd0 + pdl), hg = 2 * (ph0 + phl), wg = 2 * (pw0 + pwl);
#pragma unroll
    for (int gg = 0; gg < G; gg++) {
        float* cp = convbuf + (((size_t)(n * Cout + c0 + gg) * D + dg) * D + hg) * D + wg;
#pragma unroll
        for (int od = 0; od < 2; od++)
#pragma unroll
        for (int oh = 0; oh < 2; oh++)
#pragma unroll
        for (int ow = 0; ow < 2; ow++)
            atomicAdd(cp + (od * D + oh) * D + ow, acc[gg][(od * 2 + oh) * 2 + ow]);
    }
}

// ---------------- phase B: bias + spline + SiLU + BN + maxpool ----------------
__global__ __launch_bounds__(256) void spline_pool_kernel(
    const float* __restrict__ convbuf, // [N, Cout, D, D, D]
    const float* __restrict__ cb, const float* __restrict__ knots,
    const float* __restrict__ sw, const float* __restrict__ w1,
    const float* __restrict__ w2, const float* __restrict__ g,
    const float* __restrict__ beta,
    float* __restrict__ out,           // [N, Cout, D/2, D/2, D/2]
    int Cout, int D, int total)
{
    const int idx = blockIdx.x * 256 + threadIdx.x;
    if (idx >= total) return;
    const int P = D >> 1;
    const int pw = idx % P;
    int t = idx / P;
    const int ph = t % P;  t /= P;
    const int pd = t % P;  t /= P;
    const int c  = t % Cout;

    const float bias = cb[c];
    const float* cvb = convbuf + (((size_t)t * 0 + (size_t)(idx / (P * P * P))) * (size_t)D) * 0; // (unused)
    const float* base = convbuf + (((size_t)(idx / (P * P * P)) * (size_t)D + 2 * pd) * D + 2 * ph) * D + 2 * pw;

    float y[8];
#pragma unroll
    for (int dz = 0; dz < 2; dz++)
#pragma unroll
    for (int dy = 0; dy < 2; dy++) {
        const float2 v = *(const float2*)(base + ((size_t)dz * D + dy) * D);
        y[(dz * 2 + dy) * 2 + 0] = v.x + bias;
        y[(dz * 2 + dy) * 2 + 1] = v.y + bias;
    }

    float kn[10], sc[10];
#pragma unroll
    for (int k = 0; k < 10; k++) { kn[k] = knots[k]; sc[k] = sw[c * 10 + k]; }
    const float W1 = w1[c], W2 = w2[c];
    const float scale = g[c] * rsqrtf(1.0f + 1e-5f);
    const float bb = beta[c];

    float m = -INFINITY;
#pragma unroll
    for (int i = 0; i < 8; i++) {
        const float yy = y[i];
        float sp = 0.0f;
#pragma unroll
        for (int k = 0; k < 10; k++) {
            const float tt = fmaxf(yy - kn[k], 0.0f);
            sp = fmaf(tt * tt * tt, sc[k], sp);
        }
        const float silu = yy / (1.0f + __expf(-yy));
        const float o = fmaf(W1 * sp + W2 * silu, scale, bb);
        m = fmaxf(m, o);
    }
    out[idx] = m;
    (void)cvb;
}

// Global average pool: one wave per (n,c)
__global__ __launch_bounds__(64) void mean_kernel(
    const float* __restrict__ h, float* __restrict__ out, int S)
{
    const int nc = blockIdx.x;
    const int lane = threadIdx.x;
    const float* p = h + (size_t)nc * S;
    float s = 0.0f;
    for (int i = lane; i < S; i += 64) s += p[i];
#pragma unroll
    for (int off = 32; off > 0; off >>= 1) s += __shfl_down(s, off, 64);
    if (lane == 0) out[nc] = s / (float)S;
}

// fc1(128->256)+ReLU then fc2(256->2), batch 2
__global__ __launch_bounds__(256) void fc_kernel(
    const float* __restrict__ pooled,
    const float* __restrict__ w1, const float* __restrict__ b1,
    const float* __restrict__ w2, const float* __restrict__ b2,
    float* __restrict__ out)
{
    __shared__ float hbuf[2][256];
    const int j = threadIdx.x;
#pragma unroll
    for (int nn = 0; nn < 2; nn++) {
        float s = b1[j];
        for (int k = 0; k < 128; k++)
            s = fmaf(pooled[nn * 128 + k], w1[j * 128 + k], s);
        hbuf[nn][j] = fmaxf(s, 0.0f);
    }
    __syncthreads();
    const int wid = j >> 6, lane = j & 63;
    const int nn = wid >> 1, oo = wid & 1;
    float s = 0.0f;
    for (int k = lane; k < 256; k += 64) s += hbuf[nn][k] * w2[oo * 256 + k];
#pragma unroll
    for (int off = 32; off > 0; off >>= 1) s += __shfl_down(s, off, 64);
    if (lane == 0) out[nn * 2 + oo] = s + b2[oo];
}

extern "C" void kernel_launch(void* const* d_in, const int* in_sizes, int n_in,
                              void* d_out, int out_size, void* d_ws, size_t ws_size,
                              hipStream_t stream) {
    const float* x      = (const float*)d_in[0];
    const float* c1_w   = (const float*)d_in[1];
    const float* c1_b   = (const float*)d_in[2];
    const float* c1_kn  = (const float*)d_in[3];
    const float* c1_sw  = (const float*)d_in[4];
    const float* c1_w1  = (const float*)d_in[5];
    const float* c1_w2  = (const float*)d_in[6];
    const float* bn1_g  = (const float*)d_in[7];
    const float* bn1_b  = (const float*)d_in[8];
    const float* c2_w   = (const float*)d_in[9];
    const float* c2_b   = (const float*)d_in[10];
    const float* c2_kn  = (const float*)d_in[11];
    const float* c2_sw  = (const float*)d_in[12];
    const float* c2_w1  = (const float*)d_in[13];
    const float* c2_w2  = (const float*)d_in[14];
    const float* bn2_g  = (const float*)d_in[15];
    const float* bn2_b  = (const float*)d_in[16];
    const float* c3_w   = (const float*)d_in[17];
    const float* c3_b   = (const float*)d_in[18];
    const float* c3_kn  = (const float*)d_in[19];
    const float* c3_sw  = (const float*)d_in[20];
    const float* c3_w1  = (const float*)d_in[21];
    const float* c3_w2  = (const float*)d_in[22];
    const float* bn3_g  = (const float*)d_in[23];
    const float* bn3_b  = (const float*)d_in[24];
    const float* fc1_w  = (const float*)d_in[25];
    const float* fc1_b  = (const float*)d_in[26];
    const float* fc2_w  = (const float*)d_in[27];
    const float* fc2_b  = (const float*)d_in[28];

    float* ws = (float*)d_ws;
    float* h1       = ws;                    // 2*32*32^3 = 2,097,152 fl (8 MB)
    float* h2       = h1 + 2097152;          // 2*64*16^3 =   524,288 fl (2 MB)
    float* h3       = h2 + 524288;           // 2*128*8^3 =   131,072 fl (0.5 MB)
    float* pooled   = h3 + 131072;           // 256 fl
    float* convbuf2 = pooled + 256;          // 2*64*32^3 = 4,194,304 fl (16 MB)
    float* convbuf3 = convbuf2 + 4194304;    // 2*128*16^3 = 1,048,576 fl (4 MB)

    // zero the atomic accumulation buffers (stream-ordered, graph-capturable)
    hipMemsetAsync(convbuf2, 0, 4194304 * sizeof(float), stream);
    hipMemsetAsync(convbuf3, 0, 1048576 * sizeof(float), stream);

    // ---- L1 fused: (2,1,64^3)->(2,32,32^3). G=4, tile 4x8x8, ntiles=8*4*4=128.
    // grid = 2 * 8 * 128 = 2048 blocks of 256.
    spline_block_kernel<256, 1, 4, 4, 8, 8><<<dim3(2048), dim3(256), 0, stream>>>(
        x, c1_w, c1_b, c1_kn, c1_sw, c1_w1, c1_w2, bn1_g, bn1_b, h1,
        2, 32, 64, 64, 64, 128, 16, 4);

    // ---- L2 two-phase: (2,32,32^3)->(2,64,16^3)
    // A: chunks of 16 cin (2), G=4 (16 groups), tile 4x8x8 -> ntiles=4*2*2=16.
    // grid = 2 * 16 * 2 * 16 = 1024 blocks of 256.
    conv_partial_kernel<256, 16, 4, 4, 8, 8><<<dim3(1024), dim3(256), 0, stream>>>(
        h1, c2_w, convbuf2, 2, 32, 64, 32, 16, 4, 2, 2);
    // B: 2*64*16^3 = 524288 pooled outputs... (wait: pooled = 2*64*4096)
    spline_pool_kernel<<<dim3((2 * 64 * 4096 + 255) / 256), dim3(256), 0, stream>>>(
        convbuf2, c2_b, c2_kn, c2_sw, c2_w1, c2_w2, bn2_g, bn2_b, h2,
        64, 32, 2 * 64 * 4096);

    // ---- L3 two-phase: (2,64,16^3)->(2,128,8^3)
    // A: chunks of 16 cin (4), G=4 (32 groups), tile 2x8x8 -> ntiles=4.
    // grid = 2 * 32 * 4 * 4 = 1024 blocks of 128.
    conv_partial_kernel<128, 16, 4, 2, 8, 8><<<dim3(1024), dim3(128), 0, stream>>>(
        h2, c3_w, convbuf3, 2, 64, 128, 16, 4, 1, 1, 4);
    // B: 2*128*8^3 = 131072 pooled outputs
    spline_pool_kernel<<<dim3((2 * 128 * 512 + 255) / 256), dim3(256), 0, stream>>>(
        convbuf3, c3_b, c3_kn, c3_sw, c3_w1, c3_w2, bn3_g, bn3_b, h3,
        128, 16, 2 * 128 * 512);

    // ---- head
    mean_kernel<<<dim3(256), dim3(64), 0, stream>>>(h3, pooled, 512);
    fc_kernel<<<dim3(1), dim3(256), 0, stream>>>(pooled, fc1_w, fc1_b, fc2_w, fc2_b,
                                                 (float*)d_out);
}

// Round 6
// 1250.037 us; speedup vs baseline: 1.0191x; 1.0191x over previous
//
#include <hip/hip_runtime.h>
#include <math.h>

// ConvKAN3D: 3x [conv3d(3x3x3,pad1) -> cubic KAN spline + SiLU -> BN(eval) -> maxpool 2x2x2]
// then global mean pool + fc1/relu/fc2.
// Fully fused per layer. Block = (n, cout-group, spatial tile). Input slab staged
// per-cin into LDS via global_load_lds (zero VGPR), double-buffered; borders
// pre-zeroed so compute is branch-free. Row swizzle (+((hy>>1)&1)) spreads the
// stride-2 window reads over all 32 banks.
// Spline evaluated via prefix-sum Horner: sum_i s_i*max(y-k_i,0)^3 =
// A*y^3 - 3B*y^2 + 3C*y - D with per-(cout,segment) coeffs in an LDS table.
// G chosen per layer so the grid fills 256 CUs (L3 was 1 block/CU at G=4 -> G=1).

#define GLOBAL_AS __attribute__((address_space(1)))
#define LDS_AS    __attribute__((address_space(3)))

static __device__ __forceinline__ void async_ld4(const float* g, float* l) {
    __builtin_amdgcn_global_load_lds((const GLOBAL_AS void*)g, (LDS_AS void*)l,
                                     4, 0, 0);
}

template <int TPB_, int CIN, int G, int PDT, int PHT, int PWT>
__global__ __launch_bounds__(TPB_, 3) void spline_block_kernel(
    const float* __restrict__ x,    // [N, CIN, D, H, W]
    const float* __restrict__ cw,   // [Cout, CIN, 27]
    const float* __restrict__ cb,   // [Cout]
    const float* __restrict__ knots,// [10]
    const float* __restrict__ sw,   // [Cout, 10]
    const float* __restrict__ w1,
    const float* __restrict__ w2,
    const float* __restrict__ g,
    const float* __restrict__ beta,
    float* __restrict__ out,        // [N, Cout, D/2, H/2, W/2]
    int N, int Cout, int D, int H, int W,
    int ntiles, int nthw, int ntw)
{
    constexpr int ID    = 2 * PDT + 2;
    constexpr int IH    = 2 * PHT + 2;
    constexpr int IW    = 2 * PWT + 2;
    constexpr int PITCH = 20;
    static_assert(IW + 1 <= PITCH, "tile width + swizzle fits pitch");
    constexpr int PHYS  = ID * IH * PITCH;
    constexpr int NST   = (PHYS + TPB_ - 1) / TPB_;
    constexpr int BUFS  = (CIN > 1) ? 2 : 1;
    static_assert(NST <= 32, "mask fits u32");
    static_assert(PDT * PHT * PWT == TPB_, "one thread per pooled voxel");

    __shared__ float  tile[BUFS][PHYS];
    __shared__ float  wlds[CIN * G * 28];
    __shared__ float4 stbl[G * 11];      // spline prefix coeffs {A, 3B, 3C, D}

    const int PD = D >> 1, PH = H >> 1, PW = W >> 1;
    const int groups = Cout / G;
    const int tid = threadIdx.x;
    const int wbase = tid & ~63;

    const int bx      = blockIdx.x;
    const int tile_id = bx % ntiles;
    const int t1      = bx / ntiles;
    const int grp     = t1 % groups;
    const int n       = t1 / groups;
    const int c0      = grp * G;

    const int td  = tile_id / nthw;
    const int rem = tile_id % nthw;
    const int th_ = rem / ntw;
    const int tw_ = rem % ntw;

    // one-time LDS init: zero tiles (borders stay 0), stage weights, build spline table
    for (int i = tid; i < BUFS * PHYS; i += TPB_)
        (&tile[0][0])[i] = 0.0f;
    for (int i = tid; i < CIN * G * 27; i += TPB_) {
        const int t  = i % 27;
        const int cg = i / 27;
        const int gg = cg % G;
        const int ci = cg / G;
        wlds[cg * 28 + t] = cw[((c0 + gg) * CIN + ci) * 27 + t];
    }
    if (tid < G * 11) {
        const int gg  = tid / 11;
        const int cnt = tid % 11;
        const int c   = c0 + gg;
        float A = 0.f, B3 = 0.f, C3 = 0.f, Dd = 0.f;
        for (int i = 0; i < cnt; i++) {
            const float s = sw[c * 10 + i];
            const float k = knots[i];
            A  += s;
            B3 += 3.0f * s * k;
            C3 += 3.0f * s * k * k;
            Dd += s * k * k * k;
        }
        stbl[gg * 11 + cnt] = make_float4(A, B3, C3, Dd);
    }

    const int pwl = tid % PWT;
    const int phl = (tid / PWT) % PHT;
    const int pdl = tid / (PWT * PHT);

    const int pd0 = td * PDT, ph0 = th_ * PHT, pw0 = tw_ * PWT;
    const int d0 = 2 * pd0 - 1, h0 = 2 * ph0 - 1, w0 = 2 * pw0 - 1;

    int offg[NST];
    unsigned vmask = 0;
#pragma unroll
    for (int k = 0; k < NST; k++) {
        const int p   = tid + TPB_ * k;
        const int wxs = p % PITCH;
        const int row = p / PITCH;
        const int hy  = row % IH;
        const int dz  = row / IH;
        const int wx  = wxs - ((hy >> 1) & 1);   // undo swizzle
        const int dd = d0 + dz, hh = h0 + hy, ww = w0 + wx;
        const bool ok = (p < PHYS) & (wx >= 0) & (wx < IW) &
                        ((unsigned)dd < (unsigned)D) &
                        ((unsigned)hh < (unsigned)H) &
                        ((unsigned)ww < (unsigned)W);
        offg[k] = ok ? (dd * H + hh) * W + ww : 0;
        vmask |= (unsigned)ok << k;
    }

    const size_t chstride = (size_t)D * H * W;
    const float* xn = x + (size_t)n * CIN * chstride;

    float acc[G][8];
#pragma unroll
    for (int gg = 0; gg < G; gg++) {
        const float bias = cb[c0 + gg];
#pragma unroll
        for (int i = 0; i < 8; i++) acc[gg][i] = bias;
    }

    __syncthreads();   // zeros/weights/table visible before DMA writes land
    {
#pragma unroll
        for (int k = 0; k < NST; k++)
            if ((vmask >> k) & 1)
                async_ld4(xn + offg[k], &tile[0][TPB_ * k + wbase]);
    }
    __syncthreads();

    int cur = 0;
#pragma unroll 1
    for (int ci = 0; ci < CIN; ci++) {
        if (ci + 1 < CIN) {
            const float* xc = xn + (size_t)(ci + 1) * chstride;
#pragma unroll
            for (int k = 0; k < NST; k++)
                if ((vmask >> k) & 1)
                    async_ld4(xc + offg[k], &tile[cur ^ 1][TPB_ * k + wbase]);
        }

        const float* tb = &tile[cur][0];
        float r[64];
#pragma unroll
        for (int dz = 0; dz < 4; dz++)
#pragma unroll
        for (int dy = 0; dy < 4; dy++) {
            const int hy = 2 * phl + dy;
            const int base = ((2 * pdl + dz) * IH + hy) * PITCH + 2 * pwl +
                             ((hy >> 1) & 1);
            const float2 v0 = *(const float2*)(tb + base);
            const float2 v1 = *(const float2*)(tb + base + 2);
            r[(dz * 4 + dy) * 4 + 0] = v0.x;
            r[(dz * 4 + dy) * 4 + 1] = v0.y;
            r[(dz * 4 + dy) * 4 + 2] = v1.x;
            r[(dz * 4 + dy) * 4 + 3] = v1.y;
        }

#pragma unroll
        for (int gg = 0; gg < G; gg++) {
            const float4* w4p = (const float4*)&wlds[(ci * G + gg) * 28];
#pragma unroll
            for (int ch = 0; ch < 7; ch++) {
                const float4 wv = w4p[ch];
#pragma unroll
                for (int j = 0; j < 4; j++) {
                    const int tap = ch * 4 + j;
                    if (tap < 27) {
                        const float wvj = (j == 0) ? wv.x : (j == 1) ? wv.y
                                        : (j == 2) ? wv.z : wv.w;
                        const int kd = tap / 9, kh = (tap % 9) / 3, kw = tap % 3;
#pragma unroll
                        for (int od = 0; od < 2; od++)
#pragma unroll
                        for (int oh = 0; oh < 2; oh++)
#pragma unroll
                        for (int ow = 0; ow < 2; ow++)
                            acc[gg][(od * 2 + oh) * 2 + ow] =
                                fmaf(wvj,
                                     r[((od + kd) * 4 + (oh + kh)) * 4 + (ow + kw)],
                                     acc[gg][(od * 2 + oh) * 2 + ow]);
                    }
                }
            }
        }

        if (ci + 1 < CIN) {
            __syncthreads();
            cur ^= 1;
        }
    }

    // epilogue: spline (Horner via prefix table) + SiLU + BN affine + maxpool
    const int pdg = pd0 + pdl, phg = ph0 + phl, pwg = pw0 + pwl;
#pragma unroll
    for (int gg = 0; gg < G; gg++) {
        const int c = c0 + gg;
        const float W1 = w1[c], W2 = w2[c];
        const float scale = g[c] * rsqrtf(1.0f + 1e-5f);
        const float bb = beta[c];

        float m = -INFINITY;
#pragma unroll
        for (int i = 0; i < 8; i++) {
            const float y = acc[gg][i];
            int idx = (int)floorf((y + 1.0f) * 4.5f) + 1;
            idx = min(max(idx, 0), 10);
            const float4 cf = stbl[gg * 11 + idx];
            const float sp = ((cf.x * y - cf.y) * y + cf.z) * y - cf.w;
            const float silu = y / (1.0f + __expf(-y));
            const float o = fmaf(W1 * sp + W2 * silu, scale, bb);
            m = fmaxf(m, o);
        }
        out[((size_t)(n * Cout + c) * PD + pdg) * PH * PW + phg * PW + pwg] = m;
    }
}

// Global average pool: one wave per (n,c)
__global__ __launch_bounds__(64) void mean_kernel(
    const float* __restrict__ h, float* __restrict__ out, int S)
{
    const int nc = blockIdx.x;
    const int lane = threadIdx.x;
    const float* p = h + (size_t)nc * S;
    float s = 0.0f;
    for (int i = lane; i < S; i += 64) s += p[i];
#pragma unroll
    for (int off = 32; off > 0; off >>= 1) s += __shfl_down(s, off, 64);
    if (lane == 0) out[nc] = s / (float)S;
}

// fc1(128->256)+ReLU then fc2(256->2), batch 2
__global__ __launch_bounds__(256) void fc_kernel(
    const float* __restrict__ pooled,
    const float* __restrict__ w1, const float* __restrict__ b1,
    const float* __restrict__ w2, const float* __restrict__ b2,
    float* __restrict__ out)
{
    __shared__ float hbuf[2][256];
    const int j = threadIdx.x;
#pragma unroll
    for (int nn = 0; nn < 2; nn++) {
        float s = b1[j];
        for (int k = 0; k < 128; k++)
            s = fmaf(pooled[nn * 128 + k], w1[j * 128 + k], s);
        hbuf[nn][j] = fmaxf(s, 0.0f);
    }
    __syncthreads();
    const int wid = j >> 6, lane = j & 63;
    const int nn = wid >> 1, oo = wid & 1;
    float s = 0.0f;
    for (int k = lane; k < 256; k += 64) s += hbuf[nn][k] * w2[oo * 256 + k];
#pragma unroll
    for (int off = 32; off > 0; off >>= 1) s += __shfl_down(s, off, 64);
    if (lane == 0) out[nn * 2 + oo] = s + b2[oo];
}

extern "C" void kernel_launch(void* const* d_in, const int* in_sizes, int n_in,
                              void* d_out, int out_size, void* d_ws, size_t ws_size,
                              hipStream_t stream) {
    const float* x      = (const float*)d_in[0];
    const float* c1_w   = (const float*)d_in[1];
    const float* c1_b   = (const float*)d_in[2];
    const float* c1_kn  = (const float*)d_in[3];
    const float* c1_sw  = (const float*)d_in[4];
    const float* c1_w1  = (const float*)d_in[5];
    const float* c1_w2  = (const float*)d_in[6];
    const float* bn1_g  = (const float*)d_in[7];
    const float* bn1_b  = (const float*)d_in[8];
    const float* c2_w   = (const float*)d_in[9];
    const float* c2_b   = (const float*)d_in[10];
    const float* c2_kn  = (const float*)d_in[11];
    const float* c2_sw  = (const float*)d_in[12];
    const float* c2_w1  = (const float*)d_in[13];
    const float* c2_w2  = (const float*)d_in[14];
    const float* bn2_g  = (const float*)d_in[15];
    const float* bn2_b  = (const float*)d_in[16];
    const float* c3_w   = (const float*)d_in[17];
    const float* c3_b   = (const float*)d_in[18];
    const float* c3_kn  = (const float*)d_in[19];
    const float* c3_sw  = (const float*)d_in[20];
    const float* c3_w1  = (const float*)d_in[21];
    const float* c3_w2  = (const float*)d_in[22];
    const float* bn3_g  = (const float*)d_in[23];
    const float* bn3_b  = (const float*)d_in[24];
    const float* fc1_w  = (const float*)d_in[25];
    const float* fc1_b  = (const float*)d_in[26];
    const float* fc2_w  = (const float*)d_in[27];
    const float* fc2_b  = (const float*)d_in[28];

    float* ws = (float*)d_ws;
    float* h1     = ws;                  // 2*32*32^3 = 2,097,152 fl
    float* h2     = h1 + 2097152;        // 2*64*16^3 =   524,288 fl
    float* h3     = h2 + 524288;         // 2*128*8^3 =   131,072 fl
    float* pooled = h3 + 131072;         // 256 fl

    // L1: (2,1,64^3)->(2,32,32^3). G=4, tile 4x8x8, ntiles=8*4*4=128.
    // grid = 2 * 8 * 128 = 2048 blocks of 256.
    spline_block_kernel<256, 1, 4, 4, 8, 8><<<dim3(2048), dim3(256), 0, stream>>>(
        x, c1_w, c1_b, c1_kn, c1_sw, c1_w1, c1_w2, bn1_g, bn1_b, h1,
        2, 32, 64, 64, 64, 128, 16, 4);
    // L2: (2,32,32^3)->(2,64,16^3). G=2, tile 4x8x8, ntiles=4*2*2=16.
    // grid = 2 * 32 * 16 = 1024 blocks of 256.
    spline_block_kernel<256, 32, 2, 4, 8, 8><<<dim3(1024), dim3(256), 0, stream>>>(
        h1, c2_w, c2_b, c2_kn, c2_sw, c2_w1, c2_w2, bn2_g, bn2_b, h2,
        2, 64, 32, 32, 32, 16, 4, 2);
    // L3: (2,64,16^3)->(2,128,8^3). G=1, tile 2x8x8 (TPB=128), ntiles=4.
    // grid = 2 * 128 * 4 = 1024 blocks of 128.
    spline_block_kernel<128, 64, 1, 2, 8, 8><<<dim3(1024), dim3(128), 0, stream>>>(
        h2, c3_w, c3_b, c3_kn, c3_sw, c3_w1, c3_w2, bn3_g, bn3_b, h3,
        2, 128, 16, 16, 16, 4, 1, 1);
    // head
    mean_kernel<<<dim3(256), dim3(64), 0, stream>>>(h3, pooled, 512);
    fc_kernel<<<dim3(1), dim3(256), 0, stream>>>(pooled, fc1_w, fc1_b, fc2_w, fc2_b,
                                                 (float*)d_out);
}

// Round 7
// 1213.986 us; speedup vs baseline: 1.0494x; 1.0297x over previous
//
#include <hip/hip_runtime.h>
#include <math.h>

// ConvKAN3D: 3x [conv3d(3x3x3,pad1) -> cubic KAN spline + SiLU -> BN(eval) -> maxpool 2x2x2]
// then global mean pool + fc1/relu/fc2.
// Fully fused per layer. Block = (n, cout-group, spatial tile). Input slab staged
// per-cin into LDS via global_load_lds (zero VGPR), double-buffered; borders
// pre-zeroed so compute is branch-free. Row swizzle (+((hy>>1)&1)) spreads the
// stride-2 window reads over all 32 banks.
// Spline via prefix-sum Horner table in LDS: sum_i s_i*max(y-k_i,0)^3 =
// A*y^3 - 3B*y^2 + 3C*y - D per (cout, segment).
// NOTE: launch_bounds MUST stay (TPB,2): bounding at 3 caps VGPR<~96, spills the
// r[64] window to scratch (round 6: VGPR 84, WRITE_SIZE 37MB on a 2MB output, 3x slower).

#define GLOBAL_AS __attribute__((address_space(1)))
#define LDS_AS    __attribute__((address_space(3)))

static __device__ __forceinline__ void async_ld4(const float* g, float* l) {
    __builtin_amdgcn_global_load_lds((const GLOBAL_AS void*)g, (LDS_AS void*)l,
                                     4, 0, 0);
}

template <int TPB_, int CIN, int G, int PDT, int PHT, int PWT>
__global__ __launch_bounds__(TPB_, 2) void spline_block_kernel(
    const float* __restrict__ x,    // [N, CIN, D, H, W]
    const float* __restrict__ cw,   // [Cout, CIN, 27]
    const float* __restrict__ cb,   // [Cout]
    const float* __restrict__ knots,// [10]
    const float* __restrict__ sw,   // [Cout, 10]
    const float* __restrict__ w1,
    const float* __restrict__ w2,
    const float* __restrict__ g,
    const float* __restrict__ beta,
    float* __restrict__ out,        // [N, Cout, D/2, H/2, W/2]
    int N, int Cout, int D, int H, int W,
    int ntiles, int nthw, int ntw)
{
    constexpr int ID    = 2 * PDT + 2;
    constexpr int IH    = 2 * PHT + 2;
    constexpr int IW    = 2 * PWT + 2;
    constexpr int PITCH = 20;
    static_assert(IW + 1 <= PITCH, "tile width + swizzle fits pitch");
    constexpr int PHYS  = ID * IH * PITCH;
    constexpr int NST   = (PHYS + TPB_ - 1) / TPB_;
    constexpr int BUFS  = (CIN > 1) ? 2 : 1;
    static_assert(NST <= 32, "mask fits u32");
    static_assert(PDT * PHT * PWT == TPB_, "one thread per pooled voxel");

    __shared__ float  tile[BUFS][PHYS];
    __shared__ float  wlds[CIN * G * 28];
    __shared__ float4 stbl[G * 11];      // spline prefix coeffs {A, 3B, 3C, D}

    const int PD = D >> 1, PH = H >> 1, PW = W >> 1;
    const int groups = Cout / G;
    const int tid = threadIdx.x;
    const int wbase = tid & ~63;

    const int bx      = blockIdx.x;
    const int tile_id = bx % ntiles;
    const int t1      = bx / ntiles;
    const int grp     = t1 % groups;
    const int n       = t1 / groups;
    const int c0      = grp * G;

    const int td  = tile_id / nthw;
    const int rem = tile_id % nthw;
    const int th_ = rem / ntw;
    const int tw_ = rem % ntw;

    // one-time LDS init: zero tiles (borders stay 0), stage weights, build spline table
    for (int i = tid; i < BUFS * PHYS; i += TPB_)
        (&tile[0][0])[i] = 0.0f;
    for (int i = tid; i < CIN * G * 27; i += TPB_) {
        const int t  = i % 27;
        const int cg = i / 27;
        const int gg = cg % G;
        const int ci = cg / G;
        wlds[cg * 28 + t] = cw[((c0 + gg) * CIN + ci) * 27 + t];
    }
    if (tid < G * 11) {
        const int gg  = tid / 11;
        const int cnt = tid % 11;
        const int c   = c0 + gg;
        float A = 0.f, B3 = 0.f, C3 = 0.f, Dd = 0.f;
        for (int i = 0; i < cnt; i++) {
            const float s = sw[c * 10 + i];
            const float k = knots[i];
            A  += s;
            B3 += 3.0f * s * k;
            C3 += 3.0f * s * k * k;
            Dd += s * k * k * k;
        }
        stbl[gg * 11 + cnt] = make_float4(A, B3, C3, Dd);
    }

    const int pwl = tid % PWT;
    const int phl = (tid / PWT) % PHT;
    const int pdl = tid / (PWT * PHT);

    const int pd0 = td * PDT, ph0 = th_ * PHT, pw0 = tw_ * PWT;
    const int d0 = 2 * pd0 - 1, h0 = 2 * ph0 - 1, w0 = 2 * pw0 - 1;

    int offg[NST];
    unsigned vmask = 0;
#pragma unroll
    for (int k = 0; k < NST; k++) {
        const int p   = tid + TPB_ * k;
        const int wxs = p % PITCH;
        const int row = p / PITCH;
        const int hy  = row % IH;
        const int dz  = row / IH;
        const int wx  = wxs - ((hy >> 1) & 1);   // undo swizzle
        const int dd = d0 + dz, hh = h0 + hy, ww = w0 + wx;
        const bool ok = (p < PHYS) & (wx >= 0) & (wx < IW) &
                        ((unsigned)dd < (unsigned)D) &
                        ((unsigned)hh < (unsigned)H) &
                        ((unsigned)ww < (unsigned)W);
        offg[k] = ok ? (dd * H + hh) * W + ww : 0;
        vmask |= (unsigned)ok << k;
    }

    const size_t chstride = (size_t)D * H * W;
    const float* xn = x + (size_t)n * CIN * chstride;

    float acc[G][8];
#pragma unroll
    for (int gg = 0; gg < G; gg++) {
        const float bias = cb[c0 + gg];
#pragma unroll
        for (int i = 0; i < 8; i++) acc[gg][i] = bias;
    }

    __syncthreads();   // zeros/weights/table visible before DMA writes land
    {
#pragma unroll
        for (int k = 0; k < NST; k++)
            if ((vmask >> k) & 1)
                async_ld4(xn + offg[k], &tile[0][TPB_ * k + wbase]);
    }
    __syncthreads();

    int cur = 0;
#pragma unroll 1
    for (int ci = 0; ci < CIN; ci++) {
        if (ci + 1 < CIN) {
            const float* xc = xn + (size_t)(ci + 1) * chstride;
#pragma unroll
            for (int k = 0; k < NST; k++)
                if ((vmask >> k) & 1)
                    async_ld4(xc + offg[k], &tile[cur ^ 1][TPB_ * k + wbase]);
        }

        const float* tb = &tile[cur][0];
        float r[64];
#pragma unroll
        for (int dz = 0; dz < 4; dz++)
#pragma unroll
        for (int dy = 0; dy < 4; dy++) {
            const int hy = 2 * phl + dy;
            const int base = ((2 * pdl + dz) * IH + hy) * PITCH + 2 * pwl +
                             ((hy >> 1) & 1);
            const float2 v0 = *(const float2*)(tb + base);
            const float2 v1 = *(const float2*)(tb + base + 2);
            r[(dz * 4 + dy) * 4 + 0] = v0.x;
            r[(dz * 4 + dy) * 4 + 1] = v0.y;
            r[(dz * 4 + dy) * 4 + 2] = v1.x;
            r[(dz * 4 + dy) * 4 + 3] = v1.y;
        }

#pragma unroll
        for (int gg = 0; gg < G; gg++) {
            const float4* w4p = (const float4*)&wlds[(ci * G + gg) * 28];
#pragma unroll
            for (int ch = 0; ch < 7; ch++) {
                const float4 wv = w4p[ch];
#pragma unroll
                for (int j = 0; j < 4; j++) {
                    const int tap = ch * 4 + j;
                    if (tap < 27) {
                        const float wvj = (j == 0) ? wv.x : (j == 1) ? wv.y
                                        : (j == 2) ? wv.z : wv.w;
                        const int kd = tap / 9, kh = (tap % 9) / 3, kw = tap % 3;
#pragma unroll
                        for (int od = 0; od < 2; od++)
#pragma unroll
                        for (int oh = 0; oh < 2; oh++)
#pragma unroll
                        for (int ow = 0; ow < 2; ow++)
                            acc[gg][(od * 2 + oh) * 2 + ow] =
                                fmaf(wvj,
                                     r[((od + kd) * 4 + (oh + kh)) * 4 + (ow + kw)],
                                     acc[gg][(od * 2 + oh) * 2 + ow]);
                    }
                }
            }
        }

        if (ci + 1 < CIN) {
            __syncthreads();
            cur ^= 1;
        }
    }

    // epilogue: spline (Horner via prefix table) + SiLU + BN affine + maxpool
    const int pdg = pd0 + pdl, phg = ph0 + phl, pwg = pw0 + pwl;
#pragma unroll
    for (int gg = 0; gg < G; gg++) {
        const int c = c0 + gg;
        const float W1 = w1[c], W2 = w2[c];
        const float scale = g[c] * rsqrtf(1.0f + 1e-5f);
        const float bb = beta[c];

        float m = -INFINITY;
#pragma unroll
        for (int i = 0; i < 8; i++) {
            const float y = acc[gg][i];
            int idx = (int)floorf((y + 1.0f) * 4.5f) + 1;
            idx = min(max(idx, 0), 10);
            const float4 cf = stbl[gg * 11 + idx];
            const float sp = ((cf.x * y - cf.y) * y + cf.z) * y - cf.w;
            const float silu = y / (1.0f + __expf(-y));
            const float o = fmaf(W1 * sp + W2 * silu, scale, bb);
            m = fmaxf(m, o);
        }
        out[((size_t)(n * Cout + c) * PD + pdg) * PH * PW + phg * PW + pwg] = m;
    }
}

// Global average pool: one wave per (n,c)
__global__ __launch_bounds__(64) void mean_kernel(
    const float* __restrict__ h, float* __restrict__ out, int S)
{
    const int nc = blockIdx.x;
    const int lane = threadIdx.x;
    const float* p = h + (size_t)nc * S;
    float s = 0.0f;
    for (int i = lane; i < S; i += 64) s += p[i];
#pragma unroll
    for (int off = 32; off > 0; off >>= 1) s += __shfl_down(s, off, 64);
    if (lane == 0) out[nc] = s / (float)S;
}

// fc1(128->256)+ReLU then fc2(256->2), batch 2
__global__ __launch_bounds__(256) void fc_kernel(
    const float* __restrict__ pooled,
    const float* __restrict__ w1, const float* __restrict__ b1,
    const float* __restrict__ w2, const float* __restrict__ b2,
    float* __restrict__ out)
{
    __shared__ float hbuf[2][256];
    const int j = threadIdx.x;
#pragma unroll
    for (int nn = 0; nn < 2; nn++) {
        float s = b1[j];
        for (int k = 0; k < 128; k++)
            s = fmaf(pooled[nn * 128 + k], w1[j * 128 + k], s);
        hbuf[nn][j] = fmaxf(s, 0.0f);
    }
    __syncthreads();
    const int wid = j >> 6, lane = j & 63;
    const int nn = wid >> 1, oo = wid & 1;
    float s = 0.0f;
    for (int k = lane; k < 256; k += 64) s += hbuf[nn][k] * w2[oo * 256 + k];
#pragma unroll
    for (int off = 32; off > 0; off >>= 1) s += __shfl_down(s, off, 64);
    if (lane == 0) out[nn * 2 + oo] = s + b2[oo];
}

extern "C" void kernel_launch(void* const* d_in, const int* in_sizes, int n_in,
                              void* d_out, int out_size, void* d_ws, size_t ws_size,
                              hipStream_t stream) {
    const float* x      = (const float*)d_in[0];
    const float* c1_w   = (const float*)d_in[1];
    const float* c1_b   = (const float*)d_in[2];
    const float* c1_kn  = (const float*)d_in[3];
    const float* c1_sw  = (const float*)d_in[4];
    const float* c1_w1  = (const float*)d_in[5];
    const float* c1_w2  = (const float*)d_in[6];
    const float* bn1_g  = (const float*)d_in[7];
    const float* bn1_b  = (const float*)d_in[8];
    const float* c2_w   = (const float*)d_in[9];
    const float* c2_b   = (const float*)d_in[10];
    const float* c2_kn  = (const float*)d_in[11];
    const float* c2_sw  = (const float*)d_in[12];
    const float* c2_w1  = (const float*)d_in[13];
    const float* c2_w2  = (const float*)d_in[14];
    const float* bn2_g  = (const float*)d_in[15];
    const float* bn2_b  = (const float*)d_in[16];
    const float* c3_w   = (const float*)d_in[17];
    const float* c3_b   = (const float*)d_in[18];
    const float* c3_kn  = (const float*)d_in[19];
    const float* c3_sw  = (const float*)d_in[20];
    const float* c3_w1  = (const float*)d_in[21];
    const float* c3_w2  = (const float*)d_in[22];
    const float* bn3_g  = (const float*)d_in[23];
    const float* bn3_b  = (const float*)d_in[24];
    const float* fc1_w  = (const float*)d_in[25];
    const float* fc1_b  = (const float*)d_in[26];
    const float* fc2_w  = (const float*)d_in[27];
    const float* fc2_b  = (const float*)d_in[28];

    float* ws = (float*)d_ws;
    float* h1     = ws;                  // 2*32*32^3 = 2,097,152 fl
    float* h2     = h1 + 2097152;        // 2*64*16^3 =   524,288 fl
    float* h3     = h2 + 524288;         // 2*128*8^3 =   131,072 fl
    float* pooled = h3 + 131072;         // 256 fl

    // L1: (2,1,64^3)->(2,32,32^3). G=4, tile 4x8x8, ntiles=8*4*4=128.
    // grid = 2 * 8 * 128 = 2048 blocks of 256. LDS ~15.5 KB.
    spline_block_kernel<256, 1, 4, 4, 8, 8><<<dim3(2048), dim3(256), 0, stream>>>(
        x, c1_w, c1_b, c1_kn, c1_sw, c1_w1, c1_w2, bn1_g, bn1_b, h1,
        2, 32, 64, 64, 64, 128, 16, 4);
    // L2: (2,32,32^3)->(2,64,16^3). G=2, tile 4x8x8, ntiles=4*2*2=16.
    // grid = 2 * 32 * 16 = 1024 blocks of 256. LDS ~36.3 KB -> 4 blocks/CU.
    spline_block_kernel<256, 32, 2, 4, 8, 8><<<dim3(1024), dim3(256), 0, stream>>>(
        h1, c2_w, c2_b, c2_kn, c2_sw, c2_w1, c2_w2, bn2_g, bn2_b, h2,
        2, 64, 32, 32, 32, 16, 4, 2);
    // L3: (2,64,16^3)->(2,128,8^3). G=1, tile 2x8x8 (TPB=128), ntiles=4.
    // grid = 2 * 128 * 4 = 1024 blocks of 128. LDS ~24.7 KB.
    spline_block_kernel<128, 64, 1, 2, 8, 8><<<dim3(1024), dim3(128), 0, stream>>>(
        h2, c3_w, c3_b, c3_kn, c3_sw, c3_w1, c3_w2, bn3_g, bn3_b, h3,
        2, 128, 16, 16, 16, 4, 1, 1);
    // head
    mean_kernel<<<dim3(256), dim3(64), 0, stream>>>(h3, pooled, 512);
    fc_kernel<<<dim3(1), dim3(256), 0, stream>>>(pooled, fc1_w, fc1_b, fc2_w, fc2_b,
                                                 (float*)d_out);
}

// Round 8
// 1116.925 us; speedup vs baseline: 1.1406x; 1.0869x over previous
//
#include <hip/hip_runtime.h>
#include <math.h>

// ConvKAN3D: 3x [conv3d(3x3x3,pad1) -> cubic KAN spline + SiLU -> BN(eval) -> maxpool 2x2x2]
// then global mean pool + fc1/relu/fc2.
// Controlling resource (rounds 4/7 cross-fit): total staged bytes = blocks*slab*CIN
// through L2/L3 at ~1 TB/s effective. So: maximize couts-per-block (G), keep >=2
// blocks/CU, split cin via PARTIAL BUFFERS (never atomics - round 5: 1.86 GB HBM).
// launch_bounds MUST stay (TPB,2): cap below ~170 VGPR spills r[64] (round 6).

#define GLOBAL_AS __attribute__((address_space(1)))
#define LDS_AS    __attribute__((address_space(3)))

static __device__ __forceinline__ void async_ld4(const float* g, float* l) {
    __builtin_amdgcn_global_load_lds((const GLOBAL_AS void*)g, (LDS_AS void*)l,
                                     4, 0, 0);
}

// ---------------- fused layer kernel (L1, L2) ----------------
template <int TPB_, int CIN, int G, int PDT, int PHT, int PWT>
__global__ __launch_bounds__(TPB_, 2) void spline_block_kernel(
    const float* __restrict__ x,    // [N, CIN, D, H, W]
    const float* __restrict__ cw,   // [Cout, CIN, 27]
    const float* __restrict__ cb,   // [Cout]
    const float* __restrict__ knots,// [10]
    const float* __restrict__ sw,   // [Cout, 10]
    const float* __restrict__ w1,
    const float* __restrict__ w2,
    const float* __restrict__ g,
    const float* __restrict__ beta,
    float* __restrict__ out,        // [N, Cout, D/2, H/2, W/2]
    int N, int Cout, int D, int H, int W,
    int ntiles, int nthw, int ntw)
{
    constexpr int ID    = 2 * PDT + 2;
    constexpr int IH    = 2 * PHT + 2;
    constexpr int IW    = 2 * PWT + 2;
    constexpr int PITCH = 20;
    static_assert(IW + 1 <= PITCH, "tile width + swizzle fits pitch");
    constexpr int PHYS  = ID * IH * PITCH;
    constexpr int NST   = (PHYS + TPB_ - 1) / TPB_;
    constexpr int BUFS  = (CIN > 1) ? 2 : 1;
    static_assert(NST <= 32, "mask fits u32");
    static_assert(PDT * PHT * PWT == TPB_, "one thread per pooled voxel");

    __shared__ float  tile[BUFS][PHYS];
    __shared__ float  wlds[CIN * G * 28];
    __shared__ float4 stbl[G * 11];      // spline prefix coeffs {A, 3B, 3C, D}

    const int PD = D >> 1, PH = H >> 1, PW = W >> 1;
    const int groups = Cout / G;
    const int tid = threadIdx.x;
    const int wbase = tid & ~63;

    const int bx      = blockIdx.x;
    const int tile_id = bx % ntiles;
    const int t1      = bx / ntiles;
    const int grp     = t1 % groups;
    const int n       = t1 / groups;
    const int c0      = grp * G;

    const int td  = tile_id / nthw;
    const int rem = tile_id % nthw;
    const int th_ = rem / ntw;
    const int tw_ = rem % ntw;

    for (int i = tid; i < BUFS * PHYS; i += TPB_)
        (&tile[0][0])[i] = 0.0f;
    for (int i = tid; i < CIN * G * 27; i += TPB_) {
        const int t  = i % 27;
        const int cg = i / 27;
        const int gg = cg % G;
        const int ci = cg / G;
        wlds[cg * 28 + t] = cw[((c0 + gg) * CIN + ci) * 27 + t];
    }
    for (int i = tid; i < G * 11; i += TPB_) {
        const int gg  = i / 11;
        const int cnt = i % 11;
        const int c   = c0 + gg;
        float A = 0.f, B3 = 0.f, C3 = 0.f, Dd = 0.f;
        for (int j = 0; j < cnt; j++) {
            const float s = sw[c * 10 + j];
            const float k = knots[j];
            A  += s;
            B3 += 3.0f * s * k;
            C3 += 3.0f * s * k * k;
            Dd += s * k * k * k;
        }
        stbl[i] = make_float4(A, B3, C3, Dd);
    }

    const int pwl = tid % PWT;
    const int phl = (tid / PWT) % PHT;
    const int pdl = tid / (PWT * PHT);

    const int pd0 = td * PDT, ph0 = th_ * PHT, pw0 = tw_ * PWT;
    const int d0 = 2 * pd0 - 1, h0 = 2 * ph0 - 1, w0 = 2 * pw0 - 1;

    int offg[NST];
    unsigned vmask = 0;
#pragma unroll
    for (int k = 0; k < NST; k++) {
        const int p   = tid + TPB_ * k;
        const int wxs = p % PITCH;
        const int row = p / PITCH;
        const int hy  = row % IH;
        const int dz  = row / IH;
        const int wx  = wxs - ((hy >> 1) & 1);   // undo bank swizzle
        const int dd = d0 + dz, hh = h0 + hy, ww = w0 + wx;
        const bool ok = (p < PHYS) & (wx >= 0) & (wx < IW) &
                        ((unsigned)dd < (unsigned)D) &
                        ((unsigned)hh < (unsigned)H) &
                        ((unsigned)ww < (unsigned)W);
        offg[k] = ok ? (dd * H + hh) * W + ww : 0;
        vmask |= (unsigned)ok << k;
    }

    const size_t chstride = (size_t)D * H * W;
    const float* xn = x + (size_t)n * CIN * chstride;

    float acc[G][8];
#pragma unroll
    for (int gg = 0; gg < G; gg++) {
        const float bias = cb[c0 + gg];
#pragma unroll
        for (int i = 0; i < 8; i++) acc[gg][i] = bias;
    }

    __syncthreads();
    {
#pragma unroll
        for (int k = 0; k < NST; k++)
            if ((vmask >> k) & 1)
                async_ld4(xn + offg[k], &tile[0][TPB_ * k + wbase]);
    }
    __syncthreads();

    int cur = 0;
#pragma unroll 1
    for (int ci = 0; ci < CIN; ci++) {
        if (ci + 1 < CIN) {
            const float* xc = xn + (size_t)(ci + 1) * chstride;
#pragma unroll
            for (int k = 0; k < NST; k++)
                if ((vmask >> k) & 1)
                    async_ld4(xc + offg[k], &tile[cur ^ 1][TPB_ * k + wbase]);
        }

        const float* tb = &tile[cur][0];
        float r[64];
#pragma unroll
        for (int dz = 0; dz < 4; dz++)
#pragma unroll
        for (int dy = 0; dy < 4; dy++) {
            const int hy = 2 * phl + dy;
            const int base = ((2 * pdl + dz) * IH + hy) * PITCH + 2 * pwl +
                             ((hy >> 1) & 1);
            const float2 v0 = *(const float2*)(tb + base);
            const float2 v1 = *(const float2*)(tb + base + 2);
            r[(dz * 4 + dy) * 4 + 0] = v0.x;
            r[(dz * 4 + dy) * 4 + 1] = v0.y;
            r[(dz * 4 + dy) * 4 + 2] = v1.x;
            r[(dz * 4 + dy) * 4 + 3] = v1.y;
        }

#pragma unroll
        for (int gg = 0; gg < G; gg++) {
            const float4* w4p = (const float4*)&wlds[(ci * G + gg) * 28];
#pragma unroll
            for (int ch = 0; ch < 7; ch++) {
                const float4 wv = w4p[ch];
#pragma unroll
                for (int j = 0; j < 4; j++) {
                    const int tap = ch * 4 + j;
                    if (tap < 27) {
                        const float wvj = (j == 0) ? wv.x : (j == 1) ? wv.y
                                        : (j == 2) ? wv.z : wv.w;
                        const int kd = tap / 9, kh = (tap % 9) / 3, kw = tap % 3;
#pragma unroll
                        for (int od = 0; od < 2; od++)
#pragma unroll
                        for (int oh = 0; oh < 2; oh++)
#pragma unroll
                        for (int ow = 0; ow < 2; ow++)
                            acc[gg][(od * 2 + oh) * 2 + ow] =
                                fmaf(wvj,
                                     r[((od + kd) * 4 + (oh + kh)) * 4 + (ow + kw)],
                                     acc[gg][(od * 2 + oh) * 2 + ow]);
                    }
                }
            }
        }

        if (ci + 1 < CIN) {
            __syncthreads();
            cur ^= 1;
        }
    }

    const int pdg = pd0 + pdl, phg = ph0 + phl, pwg = pw0 + pwl;
#pragma unroll
    for (int gg = 0; gg < G; gg++) {
        const int c = c0 + gg;
        const float W1 = w1[c], W2 = w2[c];
        const float scale = g[c] * rsqrtf(1.0f + 1e-5f);
        const float bb = beta[c];

        float m = -INFINITY;
#pragma unroll
        for (int i = 0; i < 8; i++) {
            const float y = acc[gg][i];
            int idx = (int)floorf((y + 1.0f) * 4.5f) + 1;
            idx = min(max(idx, 0), 10);
            const float4 cf = stbl[gg * 11 + idx];
            const float sp = ((cf.x * y - cf.y) * y + cf.z) * y - cf.w;
            const float silu = y / (1.0f + __expf(-y));
            const float o = fmaf(W1 * sp + W2 * silu, scale, bb);
            m = fmaxf(m, o);
        }
        out[((size_t)(n * Cout + c) * PD + pdg) * PH * PW + phg * PW + pwg] = m;
    }
}

// ---------- L3 phase A: conv partial over a cin half -> partial buffer (no bias, no atomics)
template <int TPB_, int CIN, int CHUNK, int G, int PDT, int PHT, int PWT>
__global__ __launch_bounds__(TPB_, 2) void conv_partial_kernel(
    const float* __restrict__ x,    // [N, CIN, D, D, D]
    const float* __restrict__ cw,   // [Cout, CIN, 27]
    float* __restrict__ part,       // [2][N, Cout, D, D, D]
    int N, int Cout, int D,
    int ntiles, int nthw, int ntw)
{
    constexpr int ID    = 2 * PDT + 2;
    constexpr int IH    = 2 * PHT + 2;
    constexpr int IW    = 2 * PWT + 2;
    constexpr int PITCH = 20;
    static_assert(IW + 1 <= PITCH, "fits");
    constexpr int PHYS  = ID * IH * PITCH;
    constexpr int NST   = (PHYS + TPB_ - 1) / TPB_;
    static_assert(NST <= 32, "mask fits u32");
    static_assert(PDT * PHT * PWT == TPB_, "one thread per pooled voxel");

    __shared__ float tile[2][PHYS];
    __shared__ float wlds[CHUNK * G * 28];

    const int groups = Cout / G;
    const int tid = threadIdx.x;
    const int wbase = tid & ~63;

    const int bx      = blockIdx.x;
    const int tile_id = bx % ntiles;
    int t1            = bx / ntiles;
    const int half    = t1 & 1;              // cin half
    t1 >>= 1;
    const int grp     = t1 % groups;
    const int n       = t1 / groups;
    const int c0      = grp * G;
    const int cin0    = half * CHUNK;

    const int td  = tile_id / nthw;
    const int rem = tile_id % nthw;
    const int th_ = rem / ntw;
    const int tw_ = rem % ntw;

    for (int i = tid; i < 2 * PHYS; i += TPB_)
        (&tile[0][0])[i] = 0.0f;
    for (int i = tid; i < CHUNK * G * 27; i += TPB_) {
        const int t  = i % 27;
        const int cg = i / 27;
        const int gg = cg % G;
        const int ci = cg / G;
        wlds[cg * 28 + t] = cw[((c0 + gg) * CIN + cin0 + ci) * 27 + t];
    }

    const int pwl = tid % PWT;
    const int phl = (tid / PWT) % PHT;
    const int pdl = tid / (PWT * PHT);

    const int pd0 = td * PDT, ph0 = th_ * PHT, pw0 = tw_ * PWT;
    const int d0 = 2 * pd0 - 1, h0 = 2 * ph0 - 1, w0 = 2 * pw0 - 1;

    int offg[NST];
    unsigned vmask = 0;
#pragma unroll
    for (int k = 0; k < NST; k++) {
        const int p   = tid + TPB_ * k;
        const int wxs = p % PITCH;
        const int row = p / PITCH;
        const int hy  = row % IH;
        const int dz  = row / IH;
        const int wx  = wxs - ((hy >> 1) & 1);
        const int dd = d0 + dz, hh = h0 + hy, ww = w0 + wx;
        const bool ok = (p < PHYS) & (wx >= 0) & (wx < IW) &
                        ((unsigned)dd < (unsigned)D) &
                        ((unsigned)hh < (unsigned)D) &
                        ((unsigned)ww < (unsigned)D);
        offg[k] = ok ? (dd * D + hh) * D + ww : 0;
        vmask |= (unsigned)ok << k;
    }

    const size_t chstride = (size_t)D * D * D;
    const float* xn = x + ((size_t)n * CIN + cin0) * chstride;

    float acc[G][8];
#pragma unroll
    for (int gg = 0; gg < G; gg++)
#pragma unroll
        for (int i = 0; i < 8; i++) acc[gg][i] = 0.0f;

    __syncthreads();
    {
#pragma unroll
        for (int k = 0; k < NST; k++)
            if ((vmask >> k) & 1)
                async_ld4(xn + offg[k], &tile[0][TPB_ * k + wbase]);
    }
    __syncthreads();

    int cur = 0;
#pragma unroll 1
    for (int ci = 0; ci < CHUNK; ci++) {
        if (ci + 1 < CHUNK) {
            const float* xc = xn + (size_t)(ci + 1) * chstride;
#pragma unroll
            for (int k = 0; k < NST; k++)
                if ((vmask >> k) & 1)
                    async_ld4(xc + offg[k], &tile[cur ^ 1][TPB_ * k + wbase]);
        }

        const float* tb = &tile[cur][0];
        float r[64];
#pragma unroll
        for (int dz = 0; dz < 4; dz++)
#pragma unroll
        for (int dy = 0; dy < 4; dy++) {
            const int hy = 2 * phl + dy;
            const int base = ((2 * pdl + dz) * IH + hy) * PITCH + 2 * pwl +
                             ((hy >> 1) & 1);
            const float2 v0 = *(const float2*)(tb + base);
            const float2 v1 = *(const float2*)(tb + base + 2);
            r[(dz * 4 + dy) * 4 + 0] = v0.x;
            r[(dz * 4 + dy) * 4 + 1] = v0.y;
            r[(dz * 4 + dy) * 4 + 2] = v1.x;
            r[(dz * 4 + dy) * 4 + 3] = v1.y;
        }

#pragma unroll
        for (int gg = 0; gg < G; gg++) {
            const float4* w4p = (const float4*)&wlds[(ci * G + gg) * 28];
#pragma unroll
            for (int ch = 0; ch < 7; ch++) {
                const float4 wv = w4p[ch];
#pragma unroll
                for (int j = 0; j < 4; j++) {
                    const int tap = ch * 4 + j;
                    if (tap < 27) {
                        const float wvj = (j == 0) ? wv.x : (j == 1) ? wv.y
                                        : (j == 2) ? wv.z : wv.w;
                        const int kd = tap / 9, kh = (tap % 9) / 3, kw = tap % 3;
#pragma unroll
                        for (int od = 0; od < 2; od++)
#pragma unroll
                        for (int oh = 0; oh < 2; oh++)
#pragma unroll
                        for (int ow = 0; ow < 2; ow++)
                            acc[gg][(od * 2 + oh) * 2 + ow] =
                                fmaf(wvj,
                                     r[((od + kd) * 4 + (oh + kh)) * 4 + (ow + kw)],
                                     acc[gg][(od * 2 + oh) * 2 + ow]);
                    }
                }
            }
        }

        if (ci + 1 < CHUNK) {
            __syncthreads();
            cur ^= 1;
        }
    }

    // write partial pre-pool conv values (deterministic, no atomics)
    const int dg = 2 * (pd0 + pdl), hg = 2 * (ph0 + phl), wg = 2 * (pw0 + pwl);
    float* pb = part + (size_t)half * ((size_t)N * Cout * chstride);
#pragma unroll
    for (int gg = 0; gg < G; gg++) {
        float* cp = pb + (((size_t)(n * Cout + c0 + gg) * D + dg) * D + hg) * D + wg;
#pragma unroll
        for (int od = 0; od < 2; od++)
#pragma unroll
        for (int oh = 0; oh < 2; oh++) {
            float2 v = make_float2(acc[gg][(od * 2 + oh) * 2 + 0],
                                   acc[gg][(od * 2 + oh) * 2 + 1]);
            *(float2*)(cp + (od * D + oh) * D) = v;
        }
    }
}

// ---------- L3 phase B: combine 2 partials + bias + spline + SiLU + BN + maxpool
__global__ __launch_bounds__(256) void combine_spline_pool_kernel(
    const float* __restrict__ part,  // [2][N*Cout*D^3]
    const float* __restrict__ cb, const float* __restrict__ knots,
    const float* __restrict__ sw, const float* __restrict__ w1,
    const float* __restrict__ w2, const float* __restrict__ g,
    const float* __restrict__ beta,
    float* __restrict__ out,         // [N*Cout, P^3]
    int Cout, int D, int total)
{
    const int idx = blockIdx.x * 256 + threadIdx.x;
    if (idx >= total) return;
    const int P = D >> 1;
    const int pw = idx % P;
    int t = idx / P;
    const int ph = t % P;  t /= P;
    const int pd = t % P;  t /= P;
    const int nc = t;                 // n*Cout + c
    const int c  = nc % Cout;

    const size_t volume = (size_t)(D) * D * D;
    const size_t nvol   = (size_t)total / (P * P * P) * volume; // N*Cout*D^3
    const float* b0 = part + ((size_t)nc * D + 2 * pd) * D * D + (2 * ph) * D + 2 * pw;
    const float* b1 = b0 + nvol;

    const float bias = cb[c];
    float y[8];
#pragma unroll
    for (int dz = 0; dz < 2; dz++)
#pragma unroll
    for (int dy = 0; dy < 2; dy++) {
        const size_t off = ((size_t)dz * D + dy) * D;
        const float2 v0 = *(const float2*)(b0 + off);
        const float2 v1 = *(const float2*)(b1 + off);
        y[(dz * 2 + dy) * 2 + 0] = v0.x + v1.x + bias;
        y[(dz * 2 + dy) * 2 + 1] = v0.y + v1.y + bias;
    }

    float kn[10], sc[10];
#pragma unroll
    for (int k = 0; k < 10; k++) { kn[k] = knots[k]; sc[k] = sw[c * 10 + k]; }
    const float W1 = w1[c], W2 = w2[c];
    const float scale = g[c] * rsqrtf(1.0f + 1e-5f);
    const float bb = beta[c];

    float m = -INFINITY;
#pragma unroll
    for (int i = 0; i < 8; i++) {
        const float yy = y[i];
        float sp = 0.0f;
#pragma unroll
        for (int k = 0; k < 10; k++) {
            const float tt = fmaxf(yy - kn[k], 0.0f);
            sp = fmaf(tt * tt * tt, sc[k], sp);
        }
        const float silu = yy / (1.0f + __expf(-yy));
        const float o = fmaf(W1 * sp + W2 * silu, scale, bb);
        m = fmaxf(m, o);
    }
    out[idx] = m;
}

// Global average pool: one wave per (n,c)
__global__ __launch_bounds__(64) void mean_kernel(
    const float* __restrict__ h, float* __restrict__ out, int S)
{
    const int nc = blockIdx.x;
    const int lane = threadIdx.x;
    const float* p = h + (size_t)nc * S;
    float s = 0.0f;
    for (int i = lane; i < S; i += 64) s += p[i];
#pragma unroll
    for (int off = 32; off > 0; off >>= 1) s += __shfl_down(s, off, 64);
    if (lane == 0) out[nc] = s / (float)S;
}

// fc1(128->256)+ReLU then fc2(256->2), batch 2
__global__ __launch_bounds__(256) void fc_kernel(
    const float* __restrict__ pooled,
    const float* __restrict__ w1, const float* __restrict__ b1,
    const float* __restrict__ w2, const float* __restrict__ b2,
    float* __restrict__ out)
{
    __shared__ float hbuf[2][256];
    const int j = threadIdx.x;
#pragma unroll
    for (int nn = 0; nn < 2; nn++) {
        float s = b1[j];
        for (int k = 0; k < 128; k++)
            s = fmaf(pooled[nn * 128 + k], w1[j * 128 + k], s);
        hbuf[nn][j] = fmaxf(s, 0.0f);
    }
    __syncthreads();
    const int wid = j >> 6, lane = j & 63;
    const int nn = wid >> 1, oo = wid & 1;
    float s = 0.0f;
    for (int k = lane; k < 256; k += 64) s += hbuf[nn][k] * w2[oo * 256 + k];
#pragma unroll
    for (int off = 32; off > 0; off >>= 1) s += __shfl_down(s, off, 64);
    if (lane == 0) out[nn * 2 + oo] = s + b2[oo];
}

extern "C" void kernel_launch(void* const* d_in, const int* in_sizes, int n_in,
                              void* d_out, int out_size, void* d_ws, size_t ws_size,
                              hipStream_t stream) {
    const float* x      = (const float*)d_in[0];
    const float* c1_w   = (const float*)d_in[1];
    const float* c1_b   = (const float*)d_in[2];
    const float* c1_kn  = (const float*)d_in[3];
    const float* c1_sw  = (const float*)d_in[4];
    const float* c1_w1  = (const float*)d_in[5];
    const float* c1_w2  = (const float*)d_in[6];
    const float* bn1_g  = (const float*)d_in[7];
    const float* bn1_b  = (const float*)d_in[8];
    const float* c2_w   = (const float*)d_in[9];
    const float* c2_b   = (const float*)d_in[10];
    const float* c2_kn  = (const float*)d_in[11];
    const float* c2_sw  = (const float*)d_in[12];
    const float* c2_w1  = (const float*)d_in[13];
    const float* c2_w2  = (const float*)d_in[14];
    const float* bn2_g  = (const float*)d_in[15];
    const float* bn2_b  = (const float*)d_in[16];
    const float* c3_w   = (const float*)d_in[17];
    const float* c3_b   = (const float*)d_in[18];
    const float* c3_kn  = (const float*)d_in[19];
    const float* c3_sw  = (const float*)d_in[20];
    const float* c3_w1  = (const float*)d_in[21];
    const float* c3_w2  = (const float*)d_in[22];
    const float* bn3_g  = (const float*)d_in[23];
    const float* bn3_b  = (const float*)d_in[24];
    const float* fc1_w  = (const float*)d_in[25];
    const float* fc1_b  = (const float*)d_in[26];
    const float* fc2_w  = (const float*)d_in[27];
    const float* fc2_b  = (const float*)d_in[28];

    float* ws = (float*)d_ws;
    float* h1     = ws;                  // 2*32*32^3 = 2,097,152 fl
    float* h2     = h1 + 2097152;        // 2*64*16^3 =   524,288 fl
    float* h3     = h2 + 524288;         // 2*128*8^3 =   131,072 fl
    float* pooled = h3 + 131072;         // 256 fl
    float* part3  = pooled + 256;        // 2 * (2*128*16^3) = 2,097,152 fl

    // L1: (2,1,64^3)->(2,32,32^3). G=4, tile 4x8x8, ntiles=128, grid 2048 of 256.
    spline_block_kernel<256, 1, 4, 4, 8, 8><<<dim3(2048), dim3(256), 0, stream>>>(
        x, c1_w, c1_b, c1_kn, c1_sw, c1_w1, c1_w2, bn1_g, bn1_b, h1,
        2, 32, 64, 64, 64, 128, 16, 4);
    // L2: (2,32,32^3)->(2,64,16^3). G=8, tile 2x8x8, ntiles=8*2*2=32,
    // grid = 2 * (64/8) * 32 = 512 of 128. Staging 512*8.6KB*32 = 141 MB.
    spline_block_kernel<128, 32, 8, 2, 8, 8><<<dim3(512), dim3(128), 0, stream>>>(
        h1, c2_w, c2_b, c2_kn, c2_sw, c2_w1, c2_w2, bn2_g, bn2_b, h2,
        2, 64, 32, 32, 32, 32, 4, 2);
    // L3-A: (2,64,16^3) conv partials, cin halves of 32. G=4, tile 2x8x8, ntiles=4.
    // grid = 2n * (128/4) * 2halves * 4tiles = 512 of 128. Staging 141 MB.
    conv_partial_kernel<128, 64, 32, 4, 2, 8, 8><<<dim3(512), dim3(128), 0, stream>>>(
        h2, c3_w, part3, 2, 128, 16, 4, 1, 1);
    // L3-B: combine halves + bias + spline + pool -> h3 (131072 outputs)
    combine_spline_pool_kernel<<<dim3(512), dim3(256), 0, stream>>>(
        part3, c3_b, c3_kn, c3_sw, c3_w1, c3_w2, bn3_g, bn3_b, h3,
        128, 16, 131072);
    // head
    mean_kernel<<<dim3(256), dim3(64), 0, stream>>>(h3, pooled, 512);
    fc_kernel<<<dim3(1), dim3(256), 0, stream>>>(pooled, fc1_w, fc1_b, fc2_w, fc2_b,
                                                 (float*)d_out);
}

// Round 9
// 416.527 us; speedup vs baseline: 3.0584x; 2.6815x over previous
//
#include <hip/hip_runtime.h>
#include <math.h>

// ConvKAN3D: 3x [conv3d(3x3x3,pad1) -> cubic KAN spline + SiLU -> BN(eval) -> maxpool 2x2x2]
// then global mean pool + fc1/relu/fc2.
// Fused per layer (round-4 structure, best known). Staging now uses WIDTH-16
// global_load_lds: chunk grid aligned to 4-dword global boundaries (wb = w0 & ~3,
// pitch 24) so every 16B chunk is fully-valid or fully-invalid in w (W % 4 == 0);
// invalid chunks DMA from a 64B zero scratch (zbuf) -> borders auto-zeroed each
// iteration, no masks, no pre-zero, no LDS fixup.
// HARD CONSTRAINTS (measured): G<=4 with r[64] (G=8 spills: r8 WRITE 964MB);
// launch_bounds must stay (TPB,2) (r6: bounds 3 -> VGPR 84 + spill);
// never split cin via global atomics (r5: 1.86GB HBM).

#define GLOBAL_AS __attribute__((address_space(1)))
#define LDS_AS    __attribute__((address_space(3)))

static __device__ __forceinline__ void async_ld16(const float* g, float* l) {
    __builtin_amdgcn_global_load_lds((const GLOBAL_AS void*)g, (LDS_AS void*)l,
                                     16, 0, 0);
}

template <int TPB_, int CIN, int G, int PDT, int PHT, int PWT>
__global__ __launch_bounds__(TPB_, 2) void spline_block_kernel(
    const float* __restrict__ x,    // [N, CIN, D, H, W]
    const float* __restrict__ cw,   // [Cout, CIN, 27]
    const float* __restrict__ cb,   // [Cout]
    const float* __restrict__ knots,// [10]
    const float* __restrict__ sw,   // [Cout, 10]
    const float* __restrict__ w1,
    const float* __restrict__ w2,
    const float* __restrict__ g,
    const float* __restrict__ beta,
    const float* __restrict__ zbuf, // >=64B of zeros (16B aligned)
    float* __restrict__ out,        // [N, Cout, D/2, H/2, W/2]
    int N, int Cout, int D, int H, int W,
    int ntiles, int nthw, int ntw)
{
    constexpr int ID     = 2 * PDT + 2;
    constexpr int IH     = 2 * PHT + 2;
    constexpr int PITCH  = 24;                 // 6 chunks of 4 dwords
    constexpr int ROWS   = ID * IH;
    constexpr int CHUNKS = ROWS * 6;
    constexpr int PHYS   = ROWS * PITCH;       // dwords; == CHUNKS*4
    constexpr int NCH    = (CHUNKS + TPB_ - 1) / TPB_;
    constexpr int BUFS   = (CIN > 1) ? 2 : 1;
    static_assert(NCH <= 32, "mask fits u32");
    static_assert(PDT * PHT * PWT == TPB_, "one thread per pooled voxel");

    __shared__ __align__(16) float tile[BUFS][PHYS];
    __shared__ float  wlds[CIN * G * 28];
    __shared__ float4 stbl[G * 11];            // spline prefix coeffs {A,3B,3C,D}

    const int PD = D >> 1, PH = H >> 1, PW = W >> 1;
    const int groups = Cout / G;
    const int tid = threadIdx.x;

    const int bx      = blockIdx.x;
    const int tile_id = bx % ntiles;
    const int t1      = bx / ntiles;
    const int grp     = t1 % groups;
    const int n       = t1 / groups;
    const int c0      = grp * G;

    const int td  = tile_id / nthw;
    const int rem = tile_id % nthw;
    const int th_ = rem / ntw;
    const int tw_ = rem % ntw;

    // stage weights + spline table (covered by first barrier)
    for (int i = tid; i < CIN * G * 27; i += TPB_) {
        const int t  = i % 27;
        const int cg = i / 27;
        const int gg = cg % G;
        const int ci = cg / G;
        wlds[cg * 28 + t] = cw[((c0 + gg) * CIN + ci) * 27 + t];
    }
    for (int i = tid; i < G * 11; i += TPB_) {
        const int gg  = i / 11;
        const int cnt = i % 11;
        const int c   = c0 + gg;
        float A = 0.f, B3 = 0.f, C3 = 0.f, Dd = 0.f;
        for (int j = 0; j < cnt; j++) {
            const float s = sw[c * 10 + j];
            const float k = knots[j];
            A  += s;
            B3 += 3.0f * s * k;
            C3 += 3.0f * s * k * k;
            Dd += s * k * k * k;
        }
        stbl[i] = make_float4(A, B3, C3, Dd);
    }

    const int pwl = tid % PWT;
    const int phl = (tid / PWT) % PHT;
    const int pdl = tid / (PWT * PHT);

    const int pd0 = td * PDT, ph0 = th_ * PHT, pw0 = tw_ * PWT;
    const int d0 = 2 * pd0 - 1, h0 = 2 * ph0 - 1;
    const int w0 = 2 * pw0 - 1;
    const int wb = w0 & ~3;                    // 4-dword aligned chunk origin
    const int woff = w0 - wb;                  // 1 or 3

    // per-chunk global offsets + validity (static across cin)
    int off[NCH];
    unsigned vm = 0;
#pragma unroll
    for (int k = 0; k < NCH; k++) {
        const int chunk = tid + TPB_ * k;
        const int row = chunk / 6, cs = chunk - row * 6;
        const int dz = row / IH, hy = row - dz * IH;
        const int dd = d0 + dz, hh = h0 + hy;
        const int wsd = wb + cs * 4;
        const bool ok = (chunk < CHUNKS) &
                        ((unsigned)dd < (unsigned)D) &
                        ((unsigned)hh < (unsigned)H) &
                        ((unsigned)wsd < (unsigned)W);
        off[k] = ok ? (dd * H + hh) * W + wsd : 0;
        vm |= (unsigned)ok << k;
    }

    const size_t chstride = (size_t)D * H * W;
    const float* xn = x + (size_t)n * CIN * chstride;

    float acc[G][8];
#pragma unroll
    for (int gg = 0; gg < G; gg++) {
        const float bias = cb[c0 + gg];
#pragma unroll
        for (int i = 0; i < 8; i++) acc[gg][i] = bias;
    }

    __syncthreads();   // weights/table visible; (no tile pre-zero needed)

    // stage cin 0 into buf 0
    {
#pragma unroll
        for (int k = 0; k < NCH; k++) {
            const int chunk = tid + TPB_ * k;
            if ((k + 1) * TPB_ <= CHUNKS || chunk < CHUNKS) {
                const float* src = ((vm >> k) & 1) ? (xn + off[k]) : zbuf;
                async_ld16(src, &tile[0][0] + chunk * 4);
            }
        }
    }
    __syncthreads();

    int cur = 0;
#pragma unroll 1
    for (int ci = 0; ci < CIN; ci++) {
        // prefetch next cin's slab into the other buffer (async DMA)
        if (ci + 1 < CIN) {
            const float* xc = xn + (size_t)(ci + 1) * chstride;
            float* dstbuf = &tile[cur ^ (BUFS - 1)][0];
#pragma unroll
            for (int k = 0; k < NCH; k++) {
                const int chunk = tid + TPB_ * k;
                if ((k + 1) * TPB_ <= CHUNKS || chunk < CHUNKS) {
                    const float* src = ((vm >> k) & 1) ? (xc + off[k]) : zbuf;
                    async_ld16(src, dstbuf + chunk * 4);
                }
            }
        }

        // load 4x4x4 window from LDS (branch-free; borders are zeros)
        const float* tb = &tile[cur][0];
        float r[64];
#pragma unroll
        for (int dz = 0; dz < 4; dz++)
#pragma unroll
        for (int dy = 0; dy < 4; dy++) {
            const int base = ((2 * pdl + dz) * IH + (2 * phl + dy)) * PITCH +
                             woff + 2 * pwl;
            r[(dz * 4 + dy) * 4 + 0] = tb[base + 0];
            r[(dz * 4 + dy) * 4 + 1] = tb[base + 1];
            r[(dz * 4 + dy) * 4 + 2] = tb[base + 2];
            r[(dz * 4 + dy) * 4 + 3] = tb[base + 3];
        }

#pragma unroll
        for (int gg = 0; gg < G; gg++) {
            const float4* w4p = (const float4*)&wlds[(ci * G + gg) * 28];
#pragma unroll
            for (int ch = 0; ch < 7; ch++) {
                const float4 wv = w4p[ch];
#pragma unroll
                for (int j = 0; j < 4; j++) {
                    const int tap = ch * 4 + j;
                    if (tap < 27) {
                        const float wvj = (j == 0) ? wv.x : (j == 1) ? wv.y
                                        : (j == 2) ? wv.z : wv.w;
                        const int kd = tap / 9, kh = (tap % 9) / 3, kw = tap % 3;
#pragma unroll
                        for (int od = 0; od < 2; od++)
#pragma unroll
                        for (int oh = 0; oh < 2; oh++)
#pragma unroll
                        for (int ow = 0; ow < 2; ow++)
                            acc[gg][(od * 2 + oh) * 2 + ow] =
                                fmaf(wvj,
                                     r[((od + kd) * 4 + (oh + kh)) * 4 + (ow + kw)],
                                     acc[gg][(od * 2 + oh) * 2 + ow]);
                    }
                }
            }
        }

        if (ci + 1 < CIN) {
            __syncthreads();   // drain prefetch DMA; all reads of cur done
            cur ^= 1;
        }
    }

    // epilogue: spline (prefix-Horner) + SiLU + BN affine + maxpool
    const int pdg = pd0 + pdl, phg = ph0 + phl, pwg = pw0 + pwl;
#pragma unroll
    for (int gg = 0; gg < G; gg++) {
        const int c = c0 + gg;
        const float W1 = w1[c], W2 = w2[c];
        const float scale = g[c] * rsqrtf(1.0f + 1e-5f);
        const float bb = beta[c];

        float m = -INFINITY;
#pragma unroll
        for (int i = 0; i < 8; i++) {
            const float y = acc[gg][i];
            int idx = (int)floorf((y + 1.0f) * 4.5f) + 1;
            idx = min(max(idx, 0), 10);
            const float4 cf = stbl[gg * 11 + idx];
            const float sp = ((cf.x * y - cf.y) * y + cf.z) * y - cf.w;
            const float silu = y / (1.0f + __expf(-y));
            const float o = fmaf(W1 * sp + W2 * silu, scale, bb);
            m = fmaxf(m, o);
        }
        out[((size_t)(n * Cout + c) * PD + pdg) * PH * PW + phg * PW + pwg] = m;
    }
}

// Global average pool: one wave per (n,c)
__global__ __launch_bounds__(64) void mean_kernel(
    const float* __restrict__ h, float* __restrict__ out, int S)
{
    const int nc = blockIdx.x;
    const int lane = threadIdx.x;
    const float* p = h + (size_t)nc * S;
    float s = 0.0f;
    for (int i = lane; i < S; i += 64) s += p[i];
#pragma unroll
    for (int off = 32; off > 0; off >>= 1) s += __shfl_down(s, off, 64);
    if (lane == 0) out[nc] = s / (float)S;
}

// fc1(128->256)+ReLU then fc2(256->2), batch 2
__global__ __launch_bounds__(256) void fc_kernel(
    const float* __restrict__ pooled,
    const float* __restrict__ w1, const float* __restrict__ b1,
    const float* __restrict__ w2, const float* __restrict__ b2,
    float* __restrict__ out)
{
    __shared__ float hbuf[2][256];
    const int j = threadIdx.x;
#pragma unroll
    for (int nn = 0; nn < 2; nn++) {
        float s = b1[j];
        for (int k = 0; k < 128; k++)
            s = fmaf(pooled[nn * 128 + k], w1[j * 128 + k], s);
        hbuf[nn][j] = fmaxf(s, 0.0f);
    }
    __syncthreads();
    const int wid = j >> 6, lane = j & 63;
    const int nn = wid >> 1, oo = wid & 1;
    float s = 0.0f;
    for (int k = lane; k < 256; k += 64) s += hbuf[nn][k] * w2[oo * 256 + k];
#pragma unroll
    for (int off = 32; off > 0; off >>= 1) s += __shfl_down(s, off, 64);
    if (lane == 0) out[nn * 2 + oo] = s + b2[oo];
}

extern "C" void kernel_launch(void* const* d_in, const int* in_sizes, int n_in,
                              void* d_out, int out_size, void* d_ws, size_t ws_size,
                              hipStream_t stream) {
    const float* x      = (const float*)d_in[0];
    const float* c1_w   = (const float*)d_in[1];
    const float* c1_b   = (const float*)d_in[2];
    const float* c1_kn  = (const float*)d_in[3];
    const float* c1_sw  = (const float*)d_in[4];
    const float* c1_w1  = (const float*)d_in[5];
    const float* c1_w2  = (const float*)d_in[6];
    const float* bn1_g  = (const float*)d_in[7];
    const float* bn1_b  = (const float*)d_in[8];
    const float* c2_w   = (const float*)d_in[9];
    const float* c2_b   = (const float*)d_in[10];
    const float* c2_kn  = (const float*)d_in[11];
    const float* c2_sw  = (const float*)d_in[12];
    const float* c2_w1  = (const float*)d_in[13];
    const float* c2_w2  = (const float*)d_in[14];
    const float* bn2_g  = (const float*)d_in[15];
    const float* bn2_b  = (const float*)d_in[16];
    const float* c3_w   = (const float*)d_in[17];
    const float* c3_b   = (const float*)d_in[18];
    const float* c3_kn  = (const float*)d_in[19];
    const float* c3_sw  = (const float*)d_in[20];
    const float* c3_w1  = (const float*)d_in[21];
    const float* c3_w2  = (const float*)d_in[22];
    const float* bn3_g  = (const float*)d_in[23];
    const float* bn3_b  = (const float*)d_in[24];
    const float* fc1_w  = (const float*)d_in[25];
    const float* fc1_b  = (const float*)d_in[26];
    const float* fc2_w  = (const float*)d_in[27];
    const float* fc2_b  = (const float*)d_in[28];

    float* ws = (float*)d_ws;
    float* h1     = ws;                  // 2*32*32^3 = 2,097,152 fl
    float* h2     = h1 + 2097152;        // 2*64*16^3 =   524,288 fl
    float* h3     = h2 + 524288;         // 2*128*8^3 =   131,072 fl
    float* pooled = h3 + 131072;         // 256 fl
    float* zbuf   = pooled + 256;        // 64 B zeros (16B aligned)

    hipMemsetAsync(zbuf, 0, 64, stream);

    // L1: (2,1,64^3)->(2,32,32^3). G=4, tile 4x8x8, ntiles=8*4*4=128.
    // grid = 2*8*128 = 2048 of 256. LDS ~18 KB.
    spline_block_kernel<256, 1, 4, 4, 8, 8><<<dim3(2048), dim3(256), 0, stream>>>(
        x, c1_w, c1_b, c1_kn, c1_sw, c1_w1, c1_w2, bn1_g, bn1_b, zbuf, h1,
        2, 32, 64, 64, 64, 128, 16, 4);
    // L2: (2,32,32^3)->(2,64,16^3). G=4, tile 4x8x8, ntiles=4*2*2=16.
    // grid = 2*16*16 = 512 of 256. LDS ~50 KB.
    spline_block_kernel<256, 32, 4, 4, 8, 8><<<dim3(512), dim3(256), 0, stream>>>(
        h1, c2_w, c2_b, c2_kn, c2_sw, c2_w1, c2_w2, bn2_g, bn2_b, zbuf, h2,
        2, 64, 32, 32, 32, 16, 4, 2);
    // L3: (2,64,16^3)->(2,128,8^3). G=4, tile 2x8x8 (TPB=128), ntiles=4.
    // grid = 2*32*4 = 256 of 128. LDS ~50 KB.
    spline_block_kernel<128, 64, 4, 2, 8, 8><<<dim3(256), dim3(128), 0, stream>>>(
        h2, c3_w, c3_b, c3_kn, c3_sw, c3_w1, c3_w2, bn3_g, bn3_b, zbuf, h3,
        2, 128, 16, 16, 16, 4, 1, 1);
    // head
    mean_kernel<<<dim3(256), dim3(64), 0, stream>>>(h3, pooled, 512);
    fc_kernel<<<dim3(1), dim3(256), 0, stream>>>(pooled, fc1_w, fc1_b, fc2_w, fc2_b,
                                                 (float*)d_out);
}

// Round 10
// 386.188 us; speedup vs baseline: 3.2987x; 1.0786x over previous
//
#include <hip/hip_runtime.h>
#include <math.h>

// ConvKAN3D: 3x [conv3d(3x3x3,pad1) -> cubic KAN spline + SiLU -> BN(eval) -> maxpool 2x2x2]
// then global mean pool + fc1/relu/fc2.
// Fused per layer. Width-16 global_load_lds staging (4-dword-aligned chunk grid,
// invalid chunks DMA from a zero scratch buffer). DEPTH-deep ping-pong LDS pipeline:
// stage DEPTH cin slabs per barrier round while computing the previous DEPTH ->
// barrier drain amortized DEPTH-x. L3 (1 block/CU by grid) uses DEPTH=4 (~114 KB LDS).
// HARD CONSTRAINTS (measured): G<=4 with r[64] (G=8 spills: r8 WRITE 964MB);
// launch_bounds must stay (TPB,2) (r6: bounds 3 -> VGPR 84 + spill);
// never split cin via global atomics (r5: 1.86GB HBM traffic).

#define GLOBAL_AS __attribute__((address_space(1)))
#define LDS_AS    __attribute__((address_space(3)))

static __device__ __forceinline__ void async_ld16(const float* g, float* l) {
    __builtin_amdgcn_global_load_lds((const GLOBAL_AS void*)g, (LDS_AS void*)l,
                                     16, 0, 0);
}

template <int TPB_, int CIN, int DEPTH, int G, int PDT, int PHT, int PWT>
__global__ __launch_bounds__(TPB_, 2) void spline_block_kernel(
    const float* __restrict__ x,    // [N, CIN, D, H, W]
    const float* __restrict__ cw,   // [Cout, CIN, 27]
    const float* __restrict__ cb,   // [Cout]
    const float* __restrict__ knots,// [10]
    const float* __restrict__ sw,   // [Cout, 10]
    const float* __restrict__ w1,
    const float* __restrict__ w2,
    const float* __restrict__ g,
    const float* __restrict__ beta,
    const float* __restrict__ zbuf, // >=64B of zeros (16B aligned)
    float* __restrict__ out,        // [N, Cout, D/2, H/2, W/2]
    int N, int Cout, int D, int H, int W,
    int ntiles, int nthw, int ntw)
{
    constexpr int ID     = 2 * PDT + 2;
    constexpr int IH     = 2 * PHT + 2;
    constexpr int PITCH  = 24;                 // 6 chunks of 4 dwords
    constexpr int ROWS   = ID * IH;
    constexpr int CHUNKS = ROWS * 6;
    constexpr int PHYS   = ROWS * PITCH;       // dwords == CHUNKS*4
    constexpr int NCH    = (CHUNKS + TPB_ - 1) / TPB_;
    constexpr int BUFS   = (CIN > DEPTH) ? 2 : 1;
    static_assert(CIN % DEPTH == 0, "cin divisible by depth");
    static_assert(NCH <= 32, "mask fits u32");
    static_assert(PDT * PHT * PWT == TPB_, "one thread per pooled voxel");

    __shared__ __align__(16) float tile[BUFS][DEPTH][PHYS];
    __shared__ float  wlds[CIN * G * 28];
    __shared__ float4 stbl[G * 11];            // spline prefix coeffs {A,3B,3C,D}

    const int PD = D >> 1, PH = H >> 1, PW = W >> 1;
    const int groups = Cout / G;
    const int tid = threadIdx.x;

    const int bx      = blockIdx.x;
    const int tile_id = bx % ntiles;
    const int t1      = bx / ntiles;
    const int grp     = t1 % groups;
    const int n       = t1 / groups;
    const int c0      = grp * G;

    const int td  = tile_id / nthw;
    const int rem = tile_id % nthw;
    const int th_ = rem / ntw;
    const int tw_ = rem % ntw;

    // stage weights + spline table (covered by first barrier)
    for (int i = tid; i < CIN * G * 27; i += TPB_) {
        const int t  = i % 27;
        const int cg = i / 27;
        const int gg = cg % G;
        const int ci = cg / G;
        wlds[cg * 28 + t] = cw[((c0 + gg) * CIN + ci) * 27 + t];
    }
    for (int i = tid; i < G * 11; i += TPB_) {
        const int gg  = i / 11;
        const int cnt = i % 11;
        const int c   = c0 + gg;
        float A = 0.f, B3 = 0.f, C3 = 0.f, Dd = 0.f;
        for (int j = 0; j < cnt; j++) {
            const float s = sw[c * 10 + j];
            const float k = knots[j];
            A  += s;
            B3 += 3.0f * s * k;
            C3 += 3.0f * s * k * k;
            Dd += s * k * k * k;
        }
        stbl[i] = make_float4(A, B3, C3, Dd);
    }

    const int pwl = tid % PWT;
    const int phl = (tid / PWT) % PHT;
    const int pdl = tid / (PWT * PHT);

    const int pd0 = td * PDT, ph0 = th_ * PHT, pw0 = tw_ * PWT;
    const int d0 = 2 * pd0 - 1, h0 = 2 * ph0 - 1;
    const int w0 = 2 * pw0 - 1;
    const int wb = w0 & ~3;                    // 4-dword aligned chunk origin
    const int woff = w0 - wb;                  // 1 or 3

    // per-chunk global offsets + validity (static across cin)
    int off[NCH];
    unsigned vm = 0;
#pragma unroll
    for (int k = 0; k < NCH; k++) {
        const int chunk = tid + TPB_ * k;
        const int row = chunk / 6, cs = chunk - row * 6;
        const int dz = row / IH, hy = row - dz * IH;
        const int dd = d0 + dz, hh = h0 + hy;
        const int wsd = wb + cs * 4;
        const bool ok = (chunk < CHUNKS) &
                        ((unsigned)dd < (unsigned)D) &
                        ((unsigned)hh < (unsigned)H) &
                        ((unsigned)wsd < (unsigned)W);
        off[k] = ok ? (dd * H + hh) * W + wsd : 0;
        vm |= (unsigned)ok << k;
    }

    const size_t chstride = (size_t)D * H * W;
    const float* xn = x + (size_t)n * CIN * chstride;

    float acc[G][8];
#pragma unroll
    for (int gg = 0; gg < G; gg++) {
        const float bias = cb[c0 + gg];
#pragma unroll
        for (int i = 0; i < 8; i++) acc[gg][i] = bias;
    }

    __syncthreads();   // weights/table visible before first reads

    // stage batch 0 (cin 0..DEPTH-1) into group 0
#pragma unroll 1
    for (int s = 0; s < DEPTH && s < CIN; s++) {
        const float* xc = xn + (size_t)s * chstride;
        float* dst = &tile[0][s][0];
#pragma unroll
        for (int k = 0; k < NCH; k++) {
            const int chunk = tid + TPB_ * k;
            if ((k + 1) * TPB_ <= CHUNKS || chunk < CHUNKS) {
                const float* src = ((vm >> k) & 1) ? (xc + off[k]) : zbuf;
                async_ld16(src, dst + chunk * 4);
            }
        }
    }
    __syncthreads();

    int cur = 0;
#pragma unroll 1
    for (int base = 0; base < CIN; base += DEPTH) {
        // prefetch next batch into the other group (async DMA, drained at barrier)
        if (base + DEPTH < CIN) {
#pragma unroll 1
            for (int s = 0; s < DEPTH; s++) {
                const float* xc = xn + (size_t)(base + DEPTH + s) * chstride;
                float* dst = &tile[cur ^ (BUFS - 1)][s][0];
#pragma unroll
                for (int k = 0; k < NCH; k++) {
                    const int chunk = tid + TPB_ * k;
                    if ((k + 1) * TPB_ <= CHUNKS || chunk < CHUNKS) {
                        const float* src = ((vm >> k) & 1) ? (xc + off[k]) : zbuf;
                        async_ld16(src, dst + chunk * 4);
                    }
                }
            }
        }

        // compute the DEPTH staged cins
#pragma unroll 1
        for (int s = 0; s < DEPTH; s++) {
            const int ci = base + s;
            const float* tb = &tile[cur][s][0];
            float r[64];
#pragma unroll
            for (int dz = 0; dz < 4; dz++)
#pragma unroll
            for (int dy = 0; dy < 4; dy++) {
                const int rb = ((2 * pdl + dz) * IH + (2 * phl + dy)) * PITCH +
                               woff + 2 * pwl;
                r[(dz * 4 + dy) * 4 + 0] = tb[rb + 0];
                r[(dz * 4 + dy) * 4 + 1] = tb[rb + 1];
                r[(dz * 4 + dy) * 4 + 2] = tb[rb + 2];
                r[(dz * 4 + dy) * 4 + 3] = tb[rb + 3];
            }

#pragma unroll
            for (int gg = 0; gg < G; gg++) {
                const float4* w4p = (const float4*)&wlds[(ci * G + gg) * 28];
#pragma unroll
                for (int ch = 0; ch < 7; ch++) {
                    const float4 wv = w4p[ch];
#pragma unroll
                    for (int j = 0; j < 4; j++) {
                        const int tap = ch * 4 + j;
                        if (tap < 27) {
                            const float wvj = (j == 0) ? wv.x : (j == 1) ? wv.y
                                            : (j == 2) ? wv.z : wv.w;
                            const int kd = tap / 9, kh = (tap % 9) / 3, kw = tap % 3;
#pragma unroll
                            for (int od = 0; od < 2; od++)
#pragma unroll
                            for (int oh = 0; oh < 2; oh++)
#pragma unroll
                            for (int ow = 0; ow < 2; ow++)
                                acc[gg][(od * 2 + oh) * 2 + ow] =
                                    fmaf(wvj,
                                         r[((od + kd) * 4 + (oh + kh)) * 4 + (ow + kw)],
                                         acc[gg][(od * 2 + oh) * 2 + ow]);
                        }
                    }
                }
            }
        }

        if (base + DEPTH < CIN) {
            __syncthreads();   // drain prefetch DMA; all reads of cur done
            cur ^= 1;
        }
    }

    // epilogue: spline (prefix-Horner) + SiLU + BN affine + maxpool
    const int pdg = pd0 + pdl, phg = ph0 + phl, pwg = pw0 + pwl;
#pragma unroll
    for (int gg = 0; gg < G; gg++) {
        const int c = c0 + gg;
        const float W1 = w1[c], W2 = w2[c];
        const float scale = g[c] * rsqrtf(1.0f + 1e-5f);
        const float bb = beta[c];

        float m = -INFINITY;
#pragma unroll
        for (int i = 0; i < 8; i++) {
            const float y = acc[gg][i];
            int idx = (int)floorf((y + 1.0f) * 4.5f) + 1;
            idx = min(max(idx, 0), 10);
            const float4 cf = stbl[gg * 11 + idx];
            const float sp = ((cf.x * y - cf.y) * y + cf.z) * y - cf.w;
            const float silu = y / (1.0f + __expf(-y));
            const float o = fmaf(W1 * sp + W2 * silu, scale, bb);
            m = fmaxf(m, o);
        }
        out[((size_t)(n * Cout + c) * PD + pdg) * PH * PW + phg * PW + pwg] = m;
    }
}

// Global average pool: one wave per (n,c)
__global__ __launch_bounds__(64) void mean_kernel(
    const float* __restrict__ h, float* __restrict__ out, int S)
{
    const int nc = blockIdx.x;
    const int lane = threadIdx.x;
    const float* p = h + (size_t)nc * S;
    float s = 0.0f;
    for (int i = lane; i < S; i += 64) s += p[i];
#pragma unroll
    for (int off = 32; off > 0; off >>= 1) s += __shfl_down(s, off, 64);
    if (lane == 0) out[nc] = s / (float)S;
}

// fc1(128->256)+ReLU then fc2(256->2), batch 2
__global__ __launch_bounds__(256) void fc_kernel(
    const float* __restrict__ pooled,
    const float* __restrict__ w1, const float* __restrict__ b1,
    const float* __restrict__ w2, const float* __restrict__ b2,
    float* __restrict__ out)
{
    __shared__ float hbuf[2][256];
    const int j = threadIdx.x;
#pragma unroll
    for (int nn = 0; nn < 2; nn++) {
        float s = b1[j];
        for (int k = 0; k < 128; k++)
            s = fmaf(pooled[nn * 128 + k], w1[j * 128 + k], s);
        hbuf[nn][j] = fmaxf(s, 0.0f);
    }
    __syncthreads();
    const int wid = j >> 6, lane = j & 63;
    const int nn = wid >> 1, oo = wid & 1;
    float s = 0.0f;
    for (int k = lane; k < 256; k += 64) s += hbuf[nn][k] * w2[oo * 256 + k];
#pragma unroll
    for (int off = 32; off > 0; off >>= 1) s += __shfl_down(s, off, 64);
    if (lane == 0) out[nn * 2 + oo] = s + b2[oo];
}

extern "C" void kernel_launch(void* const* d_in, const int* in_sizes, int n_in,
                              void* d_out, int out_size, void* d_ws, size_t ws_size,
                              hipStream_t stream) {
    const float* x      = (const float*)d_in[0];
    const float* c1_w   = (const float*)d_in[1];
    const float* c1_b   = (const float*)d_in[2];
    const float* c1_kn  = (const float*)d_in[3];
    const float* c1_sw  = (const float*)d_in[4];
    const float* c1_w1  = (const float*)d_in[5];
    const float* c1_w2  = (const float*)d_in[6];
    const float* bn1_g  = (const float*)d_in[7];
    const float* bn1_b  = (const float*)d_in[8];
    const float* c2_w   = (const float*)d_in[9];
    const float* c2_b   = (const float*)d_in[10];
    const float* c2_kn  = (const float*)d_in[11];
    const float* c2_sw  = (const float*)d_in[12];
    const float* c2_w1  = (const float*)d_in[13];
    const float* c2_w2  = (const float*)d_in[14];
    const float* bn2_g  = (const float*)d_in[15];
    const float* bn2_b  = (const float*)d_in[16];
    const float* c3_w   = (const float*)d_in[17];
    const float* c3_b   = (const float*)d_in[18];
    const float* c3_kn  = (const float*)d_in[19];
    const float* c3_sw  = (const float*)d_in[20];
    const float* c3_w1  = (const float*)d_in[21];
    const float* c3_w2  = (const float*)d_in[22];
    const float* bn3_g  = (const float*)d_in[23];
    const float* bn3_b  = (const float*)d_in[24];
    const float* fc1_w  = (const float*)d_in[25];
    const float* fc1_b  = (const float*)d_in[26];
    const float* fc2_w  = (const float*)d_in[27];
    const float* fc2_b  = (const float*)d_in[28];

    float* ws = (float*)d_ws;
    float* h1     = ws;                  // 2*32*32^3 = 2,097,152 fl
    float* h2     = h1 + 2097152;        // 2*64*16^3 =   524,288 fl
    float* h3     = h2 + 524288;         // 2*128*8^3 =   131,072 fl
    float* pooled = h3 + 131072;         // 256 fl
    float* zbuf   = pooled + 256;        // 64 B zeros (16B aligned)

    hipMemsetAsync(zbuf, 0, 64, stream);

    // L1: (2,1,64^3)->(2,32,32^3). DEPTH=1 (CIN=1). G=4, tile 4x8x8, ntiles=128.
    // grid = 2*8*128 = 2048 of 256.
    spline_block_kernel<256, 1, 1, 4, 4, 8, 8><<<dim3(2048), dim3(256), 0, stream>>>(
        x, c1_w, c1_b, c1_kn, c1_sw, c1_w1, c1_w2, bn1_g, bn1_b, zbuf, h1,
        2, 32, 64, 64, 64, 128, 16, 4);
    // L2: (2,32,32^3)->(2,64,16^3). DEPTH=1 (unchanged: keeps 2 blocks/CU).
    // G=4, tile 4x8x8, ntiles=16. grid = 2*16*16 = 512 of 256. LDS ~50 KB.
    spline_block_kernel<256, 32, 1, 4, 4, 8, 8><<<dim3(512), dim3(256), 0, stream>>>(
        h1, c2_w, c2_b, c2_kn, c2_sw, c2_w1, c2_w2, bn2_g, bn2_b, zbuf, h2,
        2, 64, 32, 32, 32, 16, 4, 2);
    // L3: (2,64,16^3)->(2,128,8^3). DEPTH=4 ping-pong (8 slabs, ~114 KB LDS):
    // barrier per 4 cins instead of per cin. G=4, tile 2x8x8 (TPB=128), ntiles=4.
    // grid = 2*32*4 = 256 of 128 (1 block/CU by design -> LDS is free).
    spline_block_kernel<128, 64, 4, 4, 2, 8, 8><<<dim3(256), dim3(128), 0, stream>>>(
        h2, c3_w, c3_b, c3_kn, c3_sw, c3_w1, c3_w2, bn3_g, bn3_b, zbuf, h3,
        2, 128, 16, 16, 16, 4, 1, 1);
    // head
    mean_kernel<<<dim3(256), dim3(64), 0, stream>>>(h3, pooled, 512);
    fc_kernel<<<dim3(1), dim3(256), 0, stream>>>(pooled, fc1_w, fc1_b, fc2_w, fc2_b,
                                                 (float*)d_out);
}

// Round 11
// 338.105 us; speedup vs baseline: 3.7678x; 1.1422x over previous
//
#include <hip/hip_runtime.h>
#include <math.h>

// ConvKAN3D: 3x [conv3d(3x3x3,pad1) -> cubic KAN spline + SiLU -> BN(eval) -> maxpool 2x2x2]
// then global mean pool + fc1/relu/fc2.
// Fused per layer. Width-16 global_load_lds staging (4-dword-aligned chunk grid,
// invalid chunks DMA from a zero scratch buffer). CSPLIT: block = CSPLIT cin-groups
// x SP spatial threads; each group reduces its cin range into private acc, groups
// combine via one LDS reduction (r10 post-mortem: L3 was latency-bound at 1 wave/SIMD;
// cin-split is the only free parallelism axis -> 8 waves/CU).
// HARD CONSTRAINTS (measured): G<=4 with r[64] (G=8 spills: r8 WRITE 964MB);
// launch_bounds must stay (TPB,2) (r6: bounds 3 -> VGPR 84 + spill);
// never split cin via global atomics (r5: 1.86GB HBM traffic).

#define GLOBAL_AS __attribute__((address_space(1)))
#define LDS_AS    __attribute__((address_space(3)))

static __device__ __forceinline__ void async_ld16(const float* g, float* l) {
    __builtin_amdgcn_global_load_lds((const GLOBAL_AS void*)g, (LDS_AS void*)l,
                                     16, 0, 0);
}

template <int TPB_, int CIN, int CSPLIT, int G, int PDT, int PHT, int PWT>
__global__ __launch_bounds__(TPB_, 2) void spline_block_kernel(
    const float* __restrict__ x,    // [N, CIN, D, H, W]
    const float* __restrict__ cw,   // [Cout, CIN, 27]
    const float* __restrict__ cb,   // [Cout]
    const float* __restrict__ knots,// [10]
    const float* __restrict__ sw,   // [Cout, 10]
    const float* __restrict__ w1,
    const float* __restrict__ w2,
    const float* __restrict__ g,
    const float* __restrict__ beta,
    const float* __restrict__ zbuf, // >=64B of zeros (16B aligned)
    float* __restrict__ out,        // [N, Cout, D/2, H/2, W/2]
    int N, int Cout, int D, int H, int W,
    int ntiles, int nthw, int ntw)
{
    constexpr int SP     = PDT * PHT * PWT;    // spatial threads per group
    constexpr int CPG    = CIN / CSPLIT;       // cins per group
    constexpr int ID     = 2 * PDT + 2;
    constexpr int IH     = 2 * PHT + 2;
    constexpr int PITCH  = 24;                 // 6 chunks of 4 dwords
    constexpr int ROWS   = ID * IH;
    constexpr int CHUNKS = ROWS * 6;
    constexpr int PHYS   = ROWS * PITCH;       // dwords == CHUNKS*4
    constexpr int NCH    = (CHUNKS + SP - 1) / SP;
    constexpr int BUFS   = (CPG > 1) ? 2 : 1;
    static_assert(SP * CSPLIT == TPB_, "block = CSPLIT x SP");
    static_assert(CIN % CSPLIT == 0, "cin divisible");
    static_assert(NCH <= 32, "mask fits u32");
    static_assert(CSPLIT == 1 ||
                  (CSPLIT - 1) * SP * G * 8 <= CSPLIT * BUFS * PHYS,
                  "reduction scratch fits in tile");

    __shared__ __align__(16) float tile[CSPLIT][BUFS][PHYS];
    __shared__ float  wlds[CIN * G * 28];
    __shared__ float4 stbl[G * 11];            // spline prefix coeffs {A,3B,3C,D}

    const int PD = D >> 1, PH = H >> 1, PW = W >> 1;
    const int groups = Cout / G;
    const int tid  = threadIdx.x;
    const int cg   = tid / SP;                 // cin-group id
    const int stid = tid % SP;                 // spatial thread id

    const int bx      = blockIdx.x;
    const int tile_id = bx % ntiles;
    const int t1      = bx / ntiles;
    const int grp     = t1 % groups;
    const int n       = t1 / groups;
    const int c0      = grp * G;
    const int cinbase = cg * CPG;

    const int td  = tile_id / nthw;
    const int rem = tile_id % nthw;
    const int th_ = rem / ntw;
    const int tw_ = rem % ntw;

    // stage weights + spline table (covered by first barrier)
    for (int i = tid; i < CIN * G * 27; i += TPB_) {
        const int t  = i % 27;
        const int cgr = i / 27;
        const int gg = cgr % G;
        const int ci = cgr / G;
        wlds[cgr * 28 + t] = cw[((c0 + gg) * CIN + ci) * 27 + t];
    }
    for (int i = tid; i < G * 11; i += TPB_) {
        const int gg  = i / 11;
        const int cnt = i % 11;
        const int c   = c0 + gg;
        float A = 0.f, B3 = 0.f, C3 = 0.f, Dd = 0.f;
        for (int j = 0; j < cnt; j++) {
            const float s = sw[c * 10 + j];
            const float k = knots[j];
            A  += s;
            B3 += 3.0f * s * k;
            C3 += 3.0f * s * k * k;
            Dd += s * k * k * k;
        }
        stbl[i] = make_float4(A, B3, C3, Dd);
    }

    const int pwl = stid % PWT;
    const int phl = (stid / PWT) % PHT;
    const int pdl = stid / (PWT * PHT);

    const int pd0 = td * PDT, ph0 = th_ * PHT, pw0 = tw_ * PWT;
    const int d0 = 2 * pd0 - 1, h0 = 2 * ph0 - 1;
    const int w0 = 2 * pw0 - 1;
    const int wb = w0 & ~3;                    // 4-dword aligned chunk origin
    const int woff = w0 - wb;                  // 1 or 3

    // per-chunk global offsets + validity (same for all cins; spatial-tile based)
    int off[NCH];
    unsigned vm = 0;
#pragma unroll
    for (int k = 0; k < NCH; k++) {
        const int chunk = stid + SP * k;
        const int row = chunk / 6, cs = chunk - row * 6;
        const int dz = row / IH, hy = row - dz * IH;
        const int dd = d0 + dz, hh = h0 + hy;
        const int wsd = wb + cs * 4;
        const bool ok = (chunk < CHUNKS) &
                        ((unsigned)dd < (unsigned)D) &
                        ((unsigned)hh < (unsigned)H) &
                        ((unsigned)wsd < (unsigned)W);
        off[k] = ok ? (dd * H + hh) * W + wsd : 0;
        vm |= (unsigned)ok << k;
    }

    const size_t chstride = (size_t)D * H * W;
    const float* xn = x + (size_t)n * CIN * chstride;

    float acc[G][8];
#pragma unroll
    for (int gg = 0; gg < G; gg++)
#pragma unroll
        for (int i = 0; i < 8; i++) acc[gg][i] = 0.0f;

    __syncthreads();   // weights/table visible before first reads

    // each group stages its first cin into its buf 0
    {
        const float* xc = xn + (size_t)cinbase * chstride;
        float* dst = &tile[cg][0][0];
#pragma unroll
        for (int k = 0; k < NCH; k++) {
            const int chunk = stid + SP * k;
            if ((k + 1) * SP <= CHUNKS || chunk < CHUNKS) {
                const float* src = ((vm >> k) & 1) ? (xc + off[k]) : zbuf;
                async_ld16(src, dst + chunk * 4);
            }
        }
    }
    __syncthreads();

    int cur = 0;
#pragma unroll 1
    for (int s = 0; s < CPG; s++) {
        // prefetch this group's next cin into its other buffer
        if (s + 1 < CPG) {
            const float* xc = xn + (size_t)(cinbase + s + 1) * chstride;
            float* dst = &tile[cg][cur ^ (BUFS - 1)][0];
#pragma unroll
            for (int k = 0; k < NCH; k++) {
                const int chunk = stid + SP * k;
                if ((k + 1) * SP <= CHUNKS || chunk < CHUNKS) {
                    const float* src = ((vm >> k) & 1) ? (xc + off[k]) : zbuf;
                    async_ld16(src, dst + chunk * 4);
                }
            }
        }

        const int ci = cinbase + s;
        const float* tb = &tile[cg][cur][0];
        float r[64];
#pragma unroll
        for (int dz = 0; dz < 4; dz++)
#pragma unroll
        for (int dy = 0; dy < 4; dy++) {
            const int rb = ((2 * pdl + dz) * IH + (2 * phl + dy)) * PITCH +
                           woff + 2 * pwl;
            r[(dz * 4 + dy) * 4 + 0] = tb[rb + 0];
            r[(dz * 4 + dy) * 4 + 1] = tb[rb + 1];
            r[(dz * 4 + dy) * 4 + 2] = tb[rb + 2];
            r[(dz * 4 + dy) * 4 + 3] = tb[rb + 3];
        }

#pragma unroll
        for (int gg = 0; gg < G; gg++) {
            const float4* w4p = (const float4*)&wlds[(ci * G + gg) * 28];
#pragma unroll
            for (int ch = 0; ch < 7; ch++) {
                const float4 wv = w4p[ch];
#pragma unroll
                for (int j = 0; j < 4; j++) {
                    const int tap = ch * 4 + j;
                    if (tap < 27) {
                        const float wvj = (j == 0) ? wv.x : (j == 1) ? wv.y
                                        : (j == 2) ? wv.z : wv.w;
                        const int kd = tap / 9, kh = (tap % 9) / 3, kw = tap % 3;
#pragma unroll
                        for (int od = 0; od < 2; od++)
#pragma unroll
                        for (int oh = 0; oh < 2; oh++)
#pragma unroll
                        for (int ow = 0; ow < 2; ow++)
                            acc[gg][(od * 2 + oh) * 2 + ow] =
                                fmaf(wvj,
                                     r[((od + kd) * 4 + (oh + kh)) * 4 + (ow + kw)],
                                     acc[gg][(od * 2 + oh) * 2 + ow]);
                    }
                }
            }
        }

        if (s + 1 < CPG) {
            __syncthreads();   // drain DMA; all groups' reads of cur done
            cur ^= 1;
        }
    }

    // combine partial accumulators across cin-groups (scratch aliases tile)
    float* af = &acc[0][0];
    if (CSPLIT > 1) {
        __syncthreads();                        // all groups done reading tile
        float* scratch = &tile[0][0][0];
        if (cg > 0) {
#pragma unroll
            for (int idx = 0; idx < G * 8; idx++)
                scratch[(idx * (CSPLIT - 1) + (cg - 1)) * SP + stid] = af[idx];
        }
        __syncthreads();
        if (cg == 0) {
#pragma unroll
            for (int idx = 0; idx < G * 8; idx++) {
                float s = af[idx];
                for (int j = 0; j < CSPLIT - 1; j++)
                    s += scratch[(idx * (CSPLIT - 1) + j) * SP + stid];
                af[idx] = s;
            }
        }
    }

    // epilogue (group 0 only): bias + spline (prefix-Horner) + SiLU + BN + maxpool
    if (cg == 0) {
        const int pdg = pd0 + pdl, phg = ph0 + phl, pwg = pw0 + pwl;
#pragma unroll
        for (int gg = 0; gg < G; gg++) {
            const int c = c0 + gg;
            const float bias = cb[c];
            const float W1 = w1[c], W2 = w2[c];
            const float scale = g[c] * rsqrtf(1.0f + 1e-5f);
            const float bb = beta[c];

            float m = -INFINITY;
#pragma unroll
            for (int i = 0; i < 8; i++) {
                const float y = acc[gg][i] + bias;
                int idx = (int)floorf((y + 1.0f) * 4.5f) + 1;
                idx = min(max(idx, 0), 10);
                const float4 cf = stbl[gg * 11 + idx];
                const float sp = ((cf.x * y - cf.y) * y + cf.z) * y - cf.w;
                const float silu = y / (1.0f + __expf(-y));
                const float o = fmaf(W1 * sp + W2 * silu, scale, bb);
                m = fmaxf(m, o);
            }
            out[((size_t)(n * Cout + c) * PD + pdg) * PH * PW + phg * PW + pwg] = m;
        }
    }
}

// Global average pool: one wave per (n,c)
__global__ __launch_bounds__(64) void mean_kernel(
    const float* __restrict__ h, float* __restrict__ out, int S)
{
    const int nc = blockIdx.x;
    const int lane = threadIdx.x;
    const float* p = h + (size_t)nc * S;
    float s = 0.0f;
    for (int i = lane; i < S; i += 64) s += p[i];
#pragma unroll
    for (int off = 32; off > 0; off >>= 1) s += __shfl_down(s, off, 64);
    if (lane == 0) out[nc] = s / (float)S;
}

// fc1(128->256)+ReLU then fc2(256->2), batch 2
__global__ __launch_bounds__(256) void fc_kernel(
    const float* __restrict__ pooled,
    const float* __restrict__ w1, const float* __restrict__ b1,
    const float* __restrict__ w2, const float* __restrict__ b2,
    float* __restrict__ out)
{
    __shared__ float hbuf[2][256];
    const int j = threadIdx.x;
#pragma unroll
    for (int nn = 0; nn < 2; nn++) {
        float s = b1[j];
        for (int k = 0; k < 128; k++)
            s = fmaf(pooled[nn * 128 + k], w1[j * 128 + k], s);
        hbuf[nn][j] = fmaxf(s, 0.0f);
    }
    __syncthreads();
    const int wid = j >> 6, lane = j & 63;
    const int nn = wid >> 1, oo = wid & 1;
    float s = 0.0f;
    for (int k = lane; k < 256; k += 64) s += hbuf[nn][k] * w2[oo * 256 + k];
#pragma unroll
    for (int off = 32; off > 0; off >>= 1) s += __shfl_down(s, off, 64);
    if (lane == 0) out[nn * 2 + oo] = s + b2[oo];
}

extern "C" void kernel_launch(void* const* d_in, const int* in_sizes, int n_in,
                              void* d_out, int out_size, void* d_ws, size_t ws_size,
                              hipStream_t stream) {
    const float* x      = (const float*)d_in[0];
    const float* c1_w   = (const float*)d_in[1];
    const float* c1_b   = (const float*)d_in[2];
    const float* c1_kn  = (const float*)d_in[3];
    const float* c1_sw  = (const float*)d_in[4];
    const float* c1_w1  = (const float*)d_in[5];
    const float* c1_w2  = (const float*)d_in[6];
    const float* bn1_g  = (const float*)d_in[7];
    const float* bn1_b  = (const float*)d_in[8];
    const float* c2_w   = (const float*)d_in[9];
    const float* c2_b   = (const float*)d_in[10];
    const float* c2_kn  = (const float*)d_in[11];
    const float* c2_sw  = (const float*)d_in[12];
    const float* c2_w1  = (const float*)d_in[13];
    const float* c2_w2  = (const float*)d_in[14];
    const float* bn2_g  = (const float*)d_in[15];
    const float* bn2_b  = (const float*)d_in[16];
    const float* c3_w   = (const float*)d_in[17];
    const float* c3_b   = (const float*)d_in[18];
    const float* c3_kn  = (const float*)d_in[19];
    const float* c3_sw  = (const float*)d_in[20];
    const float* c3_w1  = (const float*)d_in[21];
    const float* c3_w2  = (const float*)d_in[22];
    const float* bn3_g  = (const float*)d_in[23];
    const float* bn3_b  = (const float*)d_in[24];
    const float* fc1_w  = (const float*)d_in[25];
    const float* fc1_b  = (const float*)d_in[26];
    const float* fc2_w  = (const float*)d_in[27];
    const float* fc2_b  = (const float*)d_in[28];

    float* ws = (float*)d_ws;
    float* h1     = ws;                  // 2*32*32^3 = 2,097,152 fl
    float* h2     = h1 + 2097152;        // 2*64*16^3 =   524,288 fl
    float* h3     = h2 + 524288;         // 2*128*8^3 =   131,072 fl
    float* pooled = h3 + 131072;         // 256 fl
    float* zbuf   = pooled + 256;        // 64 B zeros (16B aligned)

    hipMemsetAsync(zbuf, 0, 64, stream);

    // L1: (2,1,64^3)->(2,32,32^3). CSPLIT=1, G=4, tile 4x8x8, ntiles=128.
    // grid = 2*8*128 = 2048 of 256. (unchanged from r10)
    spline_block_kernel<256, 1, 1, 4, 4, 8, 8><<<dim3(2048), dim3(256), 0, stream>>>(
        x, c1_w, c1_b, c1_kn, c1_sw, c1_w1, c1_w2, bn1_g, bn1_b, zbuf, h1,
        2, 32, 64, 64, 64, 128, 16, 4);
    // L2: (2,32,32^3)->(2,64,16^3). CSPLIT=1, G=4, tile 4x8x8, ntiles=16.
    // grid = 2*16*16 = 512 of 256. (unchanged from r10)
    spline_block_kernel<256, 32, 1, 4, 4, 8, 8><<<dim3(512), dim3(256), 0, stream>>>(
        h1, c2_w, c2_b, c2_kn, c2_sw, c2_w1, c2_w2, bn2_g, bn2_b, zbuf, h2,
        2, 64, 32, 32, 32, 16, 4, 2);
    // L3: (2,64,16^3)->(2,128,8^3). CSPLIT=4 x tile 2x4x8 (SP=64) = TPB 256.
    // ntiles = (8/2)*(8/4)*(8/8) = 8, grid = 2*32*8 = 512 of 256 -> 8 waves/CU.
    // LDS ~75 KB -> 2 blocks/CU. Each group handles 16 cins; LDS reduction at end.
    spline_block_kernel<256, 64, 4, 4, 2, 4, 8><<<dim3(512), dim3(256), 0, stream>>>(
        h2, c3_w, c3_b, c3_kn, c3_sw, c3_w1, c3_w2, bn3_g, bn3_b, zbuf, h3,
        2, 128, 16, 16, 16, 8, 2, 1);
    // head
    mean_kernel<<<dim3(256), dim3(64), 0, stream>>>(h3, pooled, 512);
    fc_kernel<<<dim3(1), dim3(256), 0, stream>>>(pooled, fc1_w, fc1_b, fc2_w, fc2_b,
                                                 (float*)d_out);
}